// Round 11
// baseline (574.202 us; speedup 1.0000x reference)
//
#include <hip/hip_runtime.h>
#include <float.h>
#include <math.h>

#define NUM_USERS 100000
#define NUM_ITEMS 50000
#define NNODES    150000
#define DIM       64
#define NEDGE     2000000
#define BATCH     1024
#define SEL_CAP   (1 << 18)
#define LOGIT_BLOCKS 512

#define SLICES   512                    // edge slices
#define EPS      3908                   // ceil(NEDGE/SLICES) rounded to x4
#define NBUK     293                    // buckets of 512 nodes (293*512=150016)

__device__ __forceinline__ float wave_sum64(float v) {
    #pragma unroll
    for (int off = 32; off > 0; off >>= 1) v += __shfl_xor(v, off, 64);
    return v;
}

__device__ __forceinline__ float bf2f(unsigned short s) {
    return __uint_as_float(((unsigned int)s) << 16);
}
__device__ __forceinline__ unsigned short f2bf(float f) {   // RNE
    unsigned int u = __float_as_uint(f);
    return (unsigned short)((u + 0x7fffu + ((u >> 16) & 1u)) >> 16);
}

// ---- stage 1: per-slice 293-bucket histograms + u8 rank capture ---------
// 512 slices x 512 threads: tiny LDS, high occupancy, ranks stored
// coalesced (uchar4) so the placement kernel never recomputes them.

__global__ __launch_bounds__(512) void bhist_kernel(
        const int* __restrict__ row, const int* __restrict__ col,
        unsigned short* __restrict__ cntR, unsigned short* __restrict__ cntC,
        unsigned char* __restrict__ rkR, unsigned char* __restrict__ rkC) {
    __shared__ unsigned int hr[NBUK], hc[NBUK];
    int blk = blockIdx.x, t = threadIdx.x;
    for (int i = t; i < NBUK; i += 512) { hr[i] = 0; hc[i] = 0; }
    __syncthreads();
    int e0 = blk * EPS;
    int e1 = e0 + EPS; if (e1 > NEDGE) e1 = NEDGE;
    for (int base = e0 + t * 4; base < e1; base += 2048) {
        if (base + 4 <= e1) {
            int4 r4 = *(const int4*)(row + base);
            int4 c4 = *(const int4*)(col + base);
            uchar4 a, b;
            a.x = (unsigned char)atomicAdd(&hr[r4.x >> 9], 1u);
            a.y = (unsigned char)atomicAdd(&hr[r4.y >> 9], 1u);
            a.z = (unsigned char)atomicAdd(&hr[r4.z >> 9], 1u);
            a.w = (unsigned char)atomicAdd(&hr[r4.w >> 9], 1u);
            b.x = (unsigned char)atomicAdd(&hc[c4.x >> 9], 1u);
            b.y = (unsigned char)atomicAdd(&hc[c4.y >> 9], 1u);
            b.z = (unsigned char)atomicAdd(&hc[c4.z >> 9], 1u);
            b.w = (unsigned char)atomicAdd(&hc[c4.w >> 9], 1u);
            *(uchar4*)(rkR + base) = a;
            *(uchar4*)(rkC + base) = b;
        } else {
            for (int e = base; e < e1; ++e) {
                rkR[e] = (unsigned char)atomicAdd(&hr[row[e] >> 9], 1u);
                rkC[e] = (unsigned char)atomicAdd(&hc[col[e] >> 9], 1u);
            }
        }
    }
    __syncthreads();
    for (int i = t; i < NBUK; i += 512) {
        cntR[(size_t)blk * NBUK + i] = (unsigned short)hr[i];
        cntC[(size_t)blk * NBUK + i] = (unsigned short)hc[i];
    }
}

// ---- stage 2: per-bucket prefix over slices -> off arrays + bucket bases

__global__ __launch_bounds__(512) void bprefix_kernel(
        const unsigned short* __restrict__ cntR, const unsigned short* __restrict__ cntC,
        unsigned short* __restrict__ offR, unsigned short* __restrict__ offC,
        int* __restrict__ baseR, int* __restrict__ baseC) {
    const unsigned short* cnt = blockIdx.x ? cntC : cntR;
    unsigned short* off = blockIdx.x ? offC : offR;
    int* base = blockIdx.x ? baseC : baseR;
    __shared__ int tot[512], sm[512];
    int t = threadIdx.x;
    int run = 0;
    if (t < NBUK) {
        for (int s = 0; s < SLICES; ++s) {
            int v = cnt[(size_t)s * NBUK + t];
            off[(size_t)s * NBUK + t] = (unsigned short)run;
            run += v;
        }
    }
    tot[t] = (t < NBUK) ? run : 0;
    sm[t] = tot[t];
    __syncthreads();
    for (int o = 1; o < 512; o <<= 1) {
        int v = (t >= o) ? sm[t - o] : 0;
        __syncthreads();
        sm[t] += v;
        __syncthreads();
    }
    if (t < NBUK) base[t] = sm[t] - tot[t];
    if (t == NBUK - 1) base[NBUK] = sm[t];     // == NEDGE
}

// ---- stage 3: placement -- LDS-staged slice sort, burst write-out --------
// No phase-A atomics (ranks preloaded), no edge reload, no register arrays.
// 512 threads, ~32 KB LDS -> 4 blocks/CU resident.

__global__ __launch_bounds__(512) void place_kernel(
        const int* __restrict__ row, const int* __restrict__ col,
        const unsigned char* __restrict__ rkR, const unsigned char* __restrict__ rkC,
        const unsigned short* __restrict__ cntR, const unsigned short* __restrict__ cntC,
        const unsigned short* __restrict__ offR, const unsigned short* __restrict__ offC,
        const int* __restrict__ baseR, const int* __restrict__ baseC,
        const int* __restrict__ ucnt,
        unsigned short* __restrict__ midR, unsigned int* __restrict__ midC,
        int* __restrict__ n_sel, int* __restrict__ sel_col, float* __restrict__ sel_w) {
    __shared__ int lofC[NBUK], lofR[NBUK], posC[NBUK], posR[NBUK];
    __shared__ int cCl[NBUK], cRl[NBUK];
    __shared__ int scan_tmp[512];
    __shared__ unsigned int   stC[EPS];
    __shared__ unsigned short stR[EPS];
    int blk = blockIdx.x, t = threadIdx.x;
    if (t < NBUK) {
        cCl[t] = (int)cntC[(size_t)blk * NBUK + t];
        cRl[t] = (int)cntR[(size_t)blk * NBUK + t];
        posC[t] = baseC[t] + (int)offC[(size_t)blk * NBUK + t];
        posR[t] = baseR[t] + (int)offR[(size_t)blk * NBUK + t];
    }
    __syncthreads();
    scan_tmp[t] = (t < NBUK) ? cCl[t] : 0;
    __syncthreads();
    for (int o = 1; o < 512; o <<= 1) {
        int v = (t >= o) ? scan_tmp[t - o] : 0;
        __syncthreads();
        scan_tmp[t] += v;
        __syncthreads();
    }
    if (t < NBUK) lofC[t] = scan_tmp[t] - cCl[t];
    __syncthreads();
    scan_tmp[t] = (t < NBUK) ? cRl[t] : 0;
    __syncthreads();
    for (int o = 1; o < 512; o <<= 1) {
        int v = (t >= o) ? scan_tmp[t - o] : 0;
        __syncthreads();
        scan_tmp[t] += v;
        __syncthreads();
    }
    if (t < NBUK) lofR[t] = scan_tmp[t] - cRl[t];
    __syncthreads();
    int e0 = blk * EPS;
    int e1 = e0 + EPS; if (e1 > NEDGE) e1 = NEDGE;
    for (int base = e0 + t * 4; base < e1; base += 2048) {
        if (base + 4 <= e1) {
            int4 r4 = *(const int4*)(row + base);
            int4 c4 = *(const int4*)(col + base);
            uchar4 kr = *(const uchar4*)(rkR + base);
            uchar4 kc = *(const uchar4*)(rkC + base);
            stC[lofC[c4.x >> 9] + (int)kc.x] = ((unsigned int)(c4.x & 511) << 18) | (unsigned int)r4.x;
            stC[lofC[c4.y >> 9] + (int)kc.y] = ((unsigned int)(c4.y & 511) << 18) | (unsigned int)r4.y;
            stC[lofC[c4.z >> 9] + (int)kc.z] = ((unsigned int)(c4.z & 511) << 18) | (unsigned int)r4.z;
            stC[lofC[c4.w >> 9] + (int)kc.w] = ((unsigned int)(c4.w & 511) << 18) | (unsigned int)r4.w;
            stR[lofR[r4.x >> 9] + (int)kr.x] = (unsigned short)(r4.x & 511);
            stR[lofR[r4.y >> 9] + (int)kr.y] = (unsigned short)(r4.y & 511);
            stR[lofR[r4.z >> 9] + (int)kr.z] = (unsigned short)(r4.z & 511);
            stR[lofR[r4.w >> 9] + (int)kr.w] = (unsigned short)(r4.w & 511);
            int u0 = ucnt[r4.x], u1 = ucnt[r4.y], u2 = ucnt[r4.z], u3 = ucnt[r4.w];
            if (u0 > 0) { int i = atomicAdd(n_sel, 1); if (i < SEL_CAP) { sel_col[i] = c4.x; sel_w[i] = (float)u0; } }
            if (u1 > 0) { int i = atomicAdd(n_sel, 1); if (i < SEL_CAP) { sel_col[i] = c4.y; sel_w[i] = (float)u1; } }
            if (u2 > 0) { int i = atomicAdd(n_sel, 1); if (i < SEL_CAP) { sel_col[i] = c4.z; sel_w[i] = (float)u2; } }
            if (u3 > 0) { int i = atomicAdd(n_sel, 1); if (i < SEL_CAP) { sel_col[i] = c4.w; sel_w[i] = (float)u3; } }
        } else {
            for (int e = base; e < e1; ++e) {
                int r = row[e], c = col[e];
                stC[lofC[c >> 9] + (int)rkC[e]] = ((unsigned int)(c & 511) << 18) | (unsigned int)r;
                stR[lofR[r >> 9] + (int)rkR[e]] = (unsigned short)(r & 511);
                int cu = ucnt[r];
                if (cu > 0) { int i = atomicAdd(n_sel, 1); if (i < SEL_CAP) { sel_col[i] = c; sel_w[i] = (float)cu; } }
            }
        }
    }
    __syncthreads();
    int wave = t >> 6, lane = t & 63;
    for (int b = wave; b < NBUK; b += 8) {
        int n = cCl[b], lo = lofC[b], dst = posC[b];
        for (int i = lane; i < n; i += 64) midC[dst + i] = stC[lo + i];
        n = cRl[b]; lo = lofR[b]; dst = posR[b];
        for (int i = lane; i < n; i += 64) midR[dst + i] = stR[lo + i];
    }
}

// ---- stage 4a: per col-bucket: count -> scan -> rptr + permute to CSR ----

__global__ __launch_bounds__(1024) void bfinal_col_kernel(
        const unsigned int* __restrict__ midC, const int* __restrict__ baseC,
        int* __restrict__ rptr, int* __restrict__ src_sorted) {
    __shared__ int cnt[512], sm[512], cur[512];
    int b = blockIdx.x;
    int s0 = baseC[b], s1 = baseC[b + 1];
    int t = threadIdx.x;
    if (t < 512) cnt[t] = 0;
    __syncthreads();
    for (int i = s0 + t; i < s1; i += 1024) atomicAdd(&cnt[midC[i] >> 18], 1);
    __syncthreads();
    if (t < 512) sm[t] = cnt[t];
    __syncthreads();
    for (int off = 1; off < 512; off <<= 1) {
        int v = 0;
        if (t < 512 && t >= off) v = sm[t - off];
        __syncthreads();
        if (t < 512) sm[t] += v;
        __syncthreads();
    }
    if (t < 512) {
        int excl = s0 + sm[t] - cnt[t];
        int n = b * 512 + t;
        if (n < NNODES) rptr[n] = excl;
        cur[t] = excl;
    }
    if (b == NBUK - 1 && t == 0) rptr[NNODES] = s1;   // == NEDGE
    __syncthreads();
    for (int i = s0 + t; i < s1; i += 1024) {
        unsigned int v = midC[i];
        int dst = atomicAdd(&cur[v >> 18], 1);
        src_sorted[dst] = (int)(v & 0x3FFFFu);
    }
}

// ---- stage 4b: per row-bucket: count -> dinv / dinv2 ---------------------

__global__ __launch_bounds__(1024) void bfinal_row_kernel(
        const unsigned short* __restrict__ midR, const int* __restrict__ baseR,
        float* __restrict__ dinv, float* __restrict__ dinv2) {
    __shared__ int cnt[512];
    int b = blockIdx.x;
    int s0 = baseR[b], s1 = baseR[b + 1];
    int t = threadIdx.x;
    if (t < 512) cnt[t] = 0;
    __syncthreads();
    for (int i = s0 + t; i < s1; i += 1024) atomicAdd(&cnt[midR[i]], 1);
    __syncthreads();
    if (t < 512) {
        int n = b * 512 + t;
        if (n < NNODES) {
            float d = fmaxf((float)cnt[t], 1.0f);
            dinv[n] = rsqrtf(d);
            dinv2[n] = 1.0f / d;
        }
    }
}

// ---- f32 embed -> bf16 y0 = dinv * x0 -----------------------------------

__global__ void cvt_kernel(const float4* __restrict__ src, uint2* __restrict__ dst,
                           const float* __restrict__ dinv) {
    int t = blockIdx.x * blockDim.x + threadIdx.x;   // one uint2 = 4 bf16
    if (t >= NNODES * 16) return;
    float d = dinv[t >> 4];
    float4 v = src[t];
    unsigned int w0 = (unsigned int)f2bf(v.x * d) | ((unsigned int)f2bf(v.y * d) << 16);
    unsigned int w1 = (unsigned int)f2bf(v.z * d) | ((unsigned int)f2bf(v.w * d) << 16);
    dst[t] = make_uint2(w0, w1);
}

// ---- propagation in y-space: out[c] = scale[c] * sum over in-edges y[r] --

__global__ void prop_kernel(const uint2* __restrict__ x_in, uint2* __restrict__ x_out,
                            const int* __restrict__ ptr, const int* __restrict__ src,
                            const float* __restrict__ scale) {
    int gid  = blockIdx.x * blockDim.x + threadIdx.x;
    int node = gid >> 4;       // 16 lanes per node
    int sl   = gid & 15;       // lane's 4-dim slot within the row
    if (node >= NNODES) return;
    int s = ptr[node], e = ptr[node + 1];
    float a0 = 0.f, a1 = 0.f, a2 = 0.f, a3 = 0.f;
    int i = s;
    for (; i + 4 <= e; i += 4) {
        int s0 = src[i], s1 = src[i + 1], s2 = src[i + 2], s3 = src[i + 3];
        uint2 w0 = x_in[s0 * 16 + sl];
        uint2 w1 = x_in[s1 * 16 + sl];
        uint2 w2 = x_in[s2 * 16 + sl];
        uint2 w3 = x_in[s3 * 16 + sl];
        a0 += __uint_as_float(w0.x << 16); a1 += __uint_as_float(w0.x & 0xffff0000u);
        a2 += __uint_as_float(w0.y << 16); a3 += __uint_as_float(w0.y & 0xffff0000u);
        a0 += __uint_as_float(w1.x << 16); a1 += __uint_as_float(w1.x & 0xffff0000u);
        a2 += __uint_as_float(w1.y << 16); a3 += __uint_as_float(w1.y & 0xffff0000u);
        a0 += __uint_as_float(w2.x << 16); a1 += __uint_as_float(w2.x & 0xffff0000u);
        a2 += __uint_as_float(w2.y << 16); a3 += __uint_as_float(w2.y & 0xffff0000u);
        a0 += __uint_as_float(w3.x << 16); a1 += __uint_as_float(w3.x & 0xffff0000u);
        a2 += __uint_as_float(w3.y << 16); a3 += __uint_as_float(w3.y & 0xffff0000u);
    }
    for (; i < e; ++i) {
        uint2 w0 = x_in[src[i] * 16 + sl];
        a0 += __uint_as_float(w0.x << 16); a1 += __uint_as_float(w0.x & 0xffff0000u);
        a2 += __uint_as_float(w0.y << 16); a3 += __uint_as_float(w0.y & 0xffff0000u);
    }
    float sc = scale[node];
    unsigned int o0 = (unsigned int)f2bf(a0 * sc) | ((unsigned int)f2bf(a1 * sc) << 16);
    unsigned int o1 = (unsigned int)f2bf(a2 * sc) | ((unsigned int)f2bf(a3 * sc) << 16);
    x_out[node * 16 + sl] = make_uint2(o0, o1);
}

// ---- batch / softmax part (x is bf16) -----------------------------------

__global__ void ucnt_kernel(const int* __restrict__ users, int* __restrict__ ucnt) {
    int b = blockIdx.x * blockDim.x + threadIdx.x;
    if (b < BATCH) atomicAdd(&ucnt[users[b]], 1);
}

__global__ void ctx_kernel(const unsigned short* __restrict__ x, const int* __restrict__ users,
                           float* __restrict__ ctx) {
    __shared__ float sm[256];
    int lane = threadIdx.x & 63, wl = threadIdx.x >> 6;
    float acc = 0.0f;
    for (int b = wl; b < BATCH; b += 4) acc += bf2f(x[users[b] * DIM + lane]);
    sm[threadIdx.x] = acc; __syncthreads();
    if (wl == 0)
        ctx[lane] = (sm[lane] + sm[64 + lane] + sm[128 + lane] + sm[192 + lane]) * (1.0f / BATCH);
}

__global__ void logit_kernel(const unsigned short* __restrict__ x, const float* __restrict__ ctx,
                             const int* __restrict__ sel_col, const int* __restrict__ n_sel_p,
                             float* __restrict__ sel_logit, float* __restrict__ blk_max) {
    __shared__ float sm[4];
    int lane = threadIdx.x & 63, wl = threadIdx.x >> 6;
    int n = *n_sel_p; if (n > SEL_CAP) n = SEL_CAP;
    float c = ctx[lane];
    float bmax = -FLT_MAX;
    int stride = gridDim.x * 4;
    for (int idx = blockIdx.x * 4 + wl; idx < n; idx += stride) {
        int node = sel_col[idx];
        float v = bf2f(x[node * DIM + lane]) * c;
        v = wave_sum64(v);
        if (lane == 0) sel_logit[idx] = v;
        bmax = fmaxf(bmax, v);
    }
    if (lane == 0) sm[wl] = bmax;
    __syncthreads();
    if (threadIdx.x == 0)
        blk_max[blockIdx.x] = fmaxf(fmaxf(sm[0], sm[1]), fmaxf(sm[2], sm[3]));
}

__global__ void max_kernel(const float* __restrict__ blk_max, float* __restrict__ mx) {
    __shared__ float sm[256];
    int t = threadIdx.x;
    float m = fmaxf(blk_max[t], blk_max[t + 256]);
    sm[t] = m; __syncthreads();
    for (int off = 128; off > 0; off >>= 1) {
        if (t < off) sm[t] = fmaxf(sm[t], sm[t + off]);
        __syncthreads();
    }
    if (t == 0) *mx = sm[0];
}

__global__ void accum_kernel(const unsigned short* __restrict__ x, const int* __restrict__ sel_col,
                             const float* __restrict__ sel_w, const float* __restrict__ sel_logit,
                             const int* __restrict__ n_sel_p, const float* __restrict__ mx_p,
                             float* __restrict__ S, float* __restrict__ zp) {
    __shared__ float smS[4 * 64];
    __shared__ float smZ[4];
    int lane = threadIdx.x & 63, wl = threadIdx.x >> 6;
    int n = *n_sel_p; if (n > SEL_CAP) n = SEL_CAP;
    float mx = *mx_p;
    float accS = 0.0f, accZ = 0.0f;
    int stride = gridDim.x * 4;
    for (int idx = blockIdx.x * 4 + wl; idx < n; idx += stride) {
        int node = sel_col[idx];
        float w = sel_w[idx] * __expf(sel_logit[idx] - mx);
        accS = fmaf(w, bf2f(x[node * DIM + lane]), accS);
        accZ += w;
    }
    smS[wl * 64 + lane] = accS;
    if (lane == 0) smZ[wl] = accZ;
    __syncthreads();
    if (wl == 0) {
        float s = smS[lane] + smS[64 + lane] + smS[128 + lane] + smS[192 + lane];
        atomicAdd(&S[lane], s);
    }
    if (threadIdx.x == 0) atomicAdd(zp, smZ[0] + smZ[1] + smZ[2] + smZ[3]);
}

__global__ void score_kernel(const unsigned short* __restrict__ x, const int* __restrict__ users,
                             const int* __restrict__ items, const float* __restrict__ S,
                             const float* __restrict__ zp, float* __restrict__ out) {
    int gid = blockIdx.x * blockDim.x + threadIdx.x;
    int b = gid >> 6, lane = gid & 63;
    if (b >= BATCH) return;
    float z = fmaxf(*zp, 1e-12f);
    float na = S[lane] / z;
    int u = users[b], it = items[b] + NUM_USERS;
    float v = bf2f(x[u * DIM + lane]) * (bf2f(x[it * DIM + lane]) + na);
    v = wave_sum64(v);
    if (lane == 0) out[b] = 1.0f / (1.0f + __expf(-v));
}

// ---- launch -------------------------------------------------------------

extern "C" void kernel_launch(void* const* d_in, const int* in_sizes, int n_in,
                              void* d_out, int out_size, void* d_ws, size_t ws_size,
                              hipStream_t stream) {
    const float* embed = (const float*)d_in[0];
    const int*   edge  = (const int*)d_in[1];
    const int*   row   = edge;
    const int*   col   = edge + NEDGE;
    const int*   users = (const int*)d_in[2];
    const int*   items = (const int*)d_in[3];
    float*       out   = (float*)d_out;
    char*        ws    = (char*)d_ws;

    size_t off = 0;
    auto A = [&](size_t bytes) { size_t o = off; off += (bytes + 255) & ~(size_t)255; return o; };
    // big region: midC (8 MB) + midR (4 MB) during build; xa (19.2 MB) after
    size_t o_big   = A((size_t)NNODES * DIM * 2);      // 19.2 MB
    size_t o_xb    = A((size_t)NNODES * DIM * 2);      // 19.2 MB
    size_t o_src   = A((size_t)NEDGE * 4);             // 8 MB, alive thru prop
    size_t o_rkR   = A((size_t)SLICES * EPS);          // 2 MB
    size_t o_rkC   = A((size_t)SLICES * EPS);          // 2 MB
    size_t o_cntR  = A((size_t)SLICES * NBUK * 2);     // 300 KB
    size_t o_cntC  = A((size_t)SLICES * NBUK * 2);
    size_t o_offR  = A((size_t)SLICES * NBUK * 2);
    size_t o_offC  = A((size_t)SLICES * NBUK * 2);
    size_t o_baseR = A((size_t)(NBUK + 1) * 4);
    size_t o_baseC = A((size_t)(NBUK + 1) * 4);
    size_t o_selc  = A((size_t)SEL_CAP * 4);
    size_t o_selw  = A((size_t)SEL_CAP * 4);
    size_t o_sell  = A((size_t)SEL_CAP * 4);
    size_t o_zero  = off;                              // ---- zeroed block ----
    size_t o_ucnt  = A((size_t)NNODES * 4);
    size_t o_misc  = A(1024);                          // n_sel@0, mx@4, z@8, S@256
    size_t zero_bytes = off - o_zero;                  // ---- end zero -------
    size_t o_dinv  = A((size_t)NNODES * 4);
    size_t o_dinv2 = A((size_t)NNODES * 4);
    size_t o_rptr  = A((size_t)(NNODES + 1) * 4);
    size_t o_bmax  = A((size_t)LOGIT_BLOCKS * 4);
    size_t o_ctx   = A(256);

    unsigned int*   midC = (unsigned int*)(ws + o_big);                // 8 MB
    unsigned short* midR = (unsigned short*)(ws + o_big + (size_t)NEDGE * 4);  // 4 MB
    unsigned short* xa   = (unsigned short*)(ws + o_big);              // overlay after build
    unsigned short* xb   = (unsigned short*)(ws + o_xb);
    int*   srcS  = (int*)(ws + o_src);
    unsigned char* rkR = (unsigned char*)(ws + o_rkR);
    unsigned char* rkC = (unsigned char*)(ws + o_rkC);
    unsigned short* cntR = (unsigned short*)(ws + o_cntR);
    unsigned short* cntC = (unsigned short*)(ws + o_cntC);
    unsigned short* offR = (unsigned short*)(ws + o_offR);
    unsigned short* offC = (unsigned short*)(ws + o_offC);
    int*   baseR = (int*)(ws + o_baseR);
    int*   baseC = (int*)(ws + o_baseC);
    int*   selc  = (int*)(ws + o_selc);
    float* selw  = (float*)(ws + o_selw);
    float* sell  = (float*)(ws + o_sell);
    int*   ucnt  = (int*)(ws + o_ucnt);
    int*   nsel  = (int*)(ws + o_misc);
    float* mx    = (float*)(ws + o_misc + 4);
    float* zp    = (float*)(ws + o_misc + 8);
    float* S     = (float*)(ws + o_misc + 256);
    float* dinv  = (float*)(ws + o_dinv);
    float* dinv2 = (float*)(ws + o_dinv2);
    int*   rptr  = (int*)(ws + o_rptr);
    float* bmax  = (float*)(ws + o_bmax);
    float* ctx   = (float*)(ws + o_ctx);

    hipMemsetAsync(ws + o_zero, 0, zero_bytes, stream);

    ucnt_kernel<<<(BATCH + 255) / 256, 256, 0, stream>>>(users, ucnt);

    // atomic-free CSR build: bucket radix, LDS-staged burst write-out
    bhist_kernel<<<SLICES, 512, 0, stream>>>(row, col, cntR, cntC, rkR, rkC);
    bprefix_kernel<<<2, 512, 0, stream>>>(cntR, cntC, offR, offC, baseR, baseC);
    place_kernel<<<SLICES, 512, 0, stream>>>(row, col, rkR, rkC, cntR, cntC,
                                             offR, offC, baseR, baseC, ucnt,
                                             midR, midC, nsel, selc, selw);
    bfinal_col_kernel<<<NBUK, 1024, 0, stream>>>(midC, baseC, rptr, srcS);
    bfinal_row_kernel<<<NBUK, 1024, 0, stream>>>(midR, baseR, dinv, dinv2);

    // y0 = bf16(dinv*embed); layers: y->y (dinv2), y->y (dinv2), y->x (dinv)
    cvt_kernel<<<(NNODES * 16 + 255) / 256, 256, 0, stream>>>((const float4*)embed, (uint2*)xa, dinv);
    int prop_blocks = (NNODES * 16 + 255) / 256;
    prop_kernel<<<prop_blocks, 256, 0, stream>>>((const uint2*)xa, (uint2*)xb, rptr, srcS, dinv2);
    prop_kernel<<<prop_blocks, 256, 0, stream>>>((const uint2*)xb, (uint2*)xa, rptr, srcS, dinv2);
    prop_kernel<<<prop_blocks, 256, 0, stream>>>((const uint2*)xa, (uint2*)xb, rptr, srcS, dinv);
    // final x lives in xb

    // batch softmax aggregation over selected edges
    ctx_kernel<<<1, 256, 0, stream>>>(xb, users, ctx);
    logit_kernel<<<LOGIT_BLOCKS, 256, 0, stream>>>(xb, ctx, selc, nsel, sell, bmax);
    max_kernel<<<1, 256, 0, stream>>>(bmax, mx);
    accum_kernel<<<LOGIT_BLOCKS, 256, 0, stream>>>(xb, selc, selw, sell, nsel, mx, S, zp);

    // final scores
    score_kernel<<<(BATCH * 64 + 255) / 256, 256, 0, stream>>>(xb, users, items, S, zp, out);
}

// Round 12
// 442.003 us; speedup vs baseline: 1.2991x; 1.2991x over previous
//
#include <hip/hip_runtime.h>
#include <float.h>
#include <math.h>

#define NUM_USERS 100000
#define NUM_ITEMS 50000
#define NNODES    150000
#define DIM       64
#define NEDGE     2000000
#define BATCH     1024
#define SEL_CAP   (1 << 18)
#define LOGIT_BLOCKS 512

#define SLICES   512                    // edge slices (= threads in bprefix1 scan)
#define EPS      3908                   // ceil(NEDGE/SLICES) rounded to x4
#define NBUK     293                    // buckets of 512 nodes (293*512=150016)
#define SELB     977                    // ceil(NEDGE/2048) selection blocks

__device__ __forceinline__ float wave_sum64(float v) {
    #pragma unroll
    for (int off = 32; off > 0; off >>= 1) v += __shfl_xor(v, off, 64);
    return v;
}

__device__ __forceinline__ float bf2f(unsigned short s) {
    return __uint_as_float(((unsigned int)s) << 16);
}
__device__ __forceinline__ unsigned short f2bf(float f) {   // RNE
    unsigned int u = __float_as_uint(f);
    return (unsigned short)((u + 0x7fffu + ((u >> 16) & 1u)) >> 16);
}

// ---- stage 1: per-slice 293-bucket histograms + u8 rank capture ---------

__global__ __launch_bounds__(512) void bhist_kernel(
        const int* __restrict__ row, const int* __restrict__ col,
        unsigned short* __restrict__ cntR, unsigned short* __restrict__ cntC,
        unsigned char* __restrict__ rkR, unsigned char* __restrict__ rkC) {
    __shared__ unsigned int hr[NBUK], hc[NBUK];
    int blk = blockIdx.x, t = threadIdx.x;
    for (int i = t; i < NBUK; i += 512) { hr[i] = 0; hc[i] = 0; }
    __syncthreads();
    int e0 = blk * EPS;
    int e1 = e0 + EPS; if (e1 > NEDGE) e1 = NEDGE;
    for (int base = e0 + t * 4; base < e1; base += 2048) {
        if (base + 4 <= e1) {
            int4 r4 = *(const int4*)(row + base);
            int4 c4 = *(const int4*)(col + base);
            uchar4 a, b;
            a.x = (unsigned char)atomicAdd(&hr[r4.x >> 9], 1u);
            a.y = (unsigned char)atomicAdd(&hr[r4.y >> 9], 1u);
            a.z = (unsigned char)atomicAdd(&hr[r4.z >> 9], 1u);
            a.w = (unsigned char)atomicAdd(&hr[r4.w >> 9], 1u);
            b.x = (unsigned char)atomicAdd(&hc[c4.x >> 9], 1u);
            b.y = (unsigned char)atomicAdd(&hc[c4.y >> 9], 1u);
            b.z = (unsigned char)atomicAdd(&hc[c4.z >> 9], 1u);
            b.w = (unsigned char)atomicAdd(&hc[c4.w >> 9], 1u);
            *(uchar4*)(rkR + base) = a;
            *(uchar4*)(rkC + base) = b;
        } else {
            for (int e = base; e < e1; ++e) {
                rkR[e] = (unsigned char)atomicAdd(&hr[row[e] >> 9], 1u);
                rkC[e] = (unsigned char)atomicAdd(&hc[col[e] >> 9], 1u);
            }
        }
    }
    __syncthreads();
    for (int i = t; i < NBUK; i += 512) {
        cntR[(size_t)blk * NBUK + i] = (unsigned short)hr[i];
        cntC[(size_t)blk * NBUK + i] = (unsigned short)hc[i];
    }
}

// ---- stage 2: parallel per-bucket prefix over slices ---------------------
// bprefix1: one block per (side,bucket), 512-thread scan over slices.
// bprefix2: scan of bucket totals -> bucket bases.

__global__ __launch_bounds__(512) void bprefix1_kernel(
        const unsigned short* __restrict__ cntR, const unsigned short* __restrict__ cntC,
        unsigned short* __restrict__ offR, unsigned short* __restrict__ offC,
        int* __restrict__ totRC) {
    int side = blockIdx.x / NBUK;
    int b = blockIdx.x - side * NBUK;
    const unsigned short* cnt = side ? cntC : cntR;
    unsigned short* off = side ? offC : offR;
    __shared__ int sm[512];
    int t = threadIdx.x;
    int v = (int)cnt[(size_t)t * NBUK + b];
    sm[t] = v;
    __syncthreads();
    for (int o = 1; o < 512; o <<= 1) {
        int x = (t >= o) ? sm[t - o] : 0;
        __syncthreads();
        sm[t] += x;
        __syncthreads();
    }
    off[(size_t)t * NBUK + b] = (unsigned short)(sm[t] - v);
    if (t == 511) totRC[side * NBUK + b] = sm[511];
}

__global__ __launch_bounds__(512) void bprefix2_kernel(
        const int* __restrict__ totRC, int* __restrict__ baseR, int* __restrict__ baseC) {
    const int* tot = totRC + blockIdx.x * NBUK;
    int* base = blockIdx.x ? baseC : baseR;
    __shared__ int sm[512];
    int t = threadIdx.x;
    int v = (t < NBUK) ? tot[t] : 0;
    sm[t] = v;
    __syncthreads();
    for (int o = 1; o < 512; o <<= 1) {
        int x = (t >= o) ? sm[t - o] : 0;
        __syncthreads();
        sm[t] += x;
        __syncthreads();
    }
    if (t < NBUK) base[t] = sm[t] - v;
    if (t == NBUK - 1) base[NBUK] = sm[t];     // == NEDGE
}

// ---- batch-edge selection (standalone, low-atomic) -----------------------
// Block-local LDS compaction; ONE global atomic per block (977 total).

__global__ __launch_bounds__(256) void select_kernel(
        const int* __restrict__ row, const int* __restrict__ col,
        const int* __restrict__ ucnt,
        int* __restrict__ n_sel, int* __restrict__ sel_col, float* __restrict__ sel_w) {
    __shared__ int lcnt, lbase;
    __shared__ int2 buf[512];
    if (threadIdx.x == 0) lcnt = 0;
    __syncthreads();
    int e0 = blockIdx.x * 2048;
    int e1 = e0 + 2048; if (e1 > NEDGE) e1 = NEDGE;
    for (int base = e0 + (int)threadIdx.x * 4; base < e1; base += 1024) {
        if (base + 4 <= e1) {
            int4 r4 = *(const int4*)(row + base);
            int4 c4 = *(const int4*)(col + base);
            int u0 = ucnt[r4.x], u1 = ucnt[r4.y], u2 = ucnt[r4.z], u3 = ucnt[r4.w];
            if (u0 > 0) { int i = atomicAdd(&lcnt, 1); if (i < 512) buf[i] = make_int2(c4.x, u0); }
            if (u1 > 0) { int i = atomicAdd(&lcnt, 1); if (i < 512) buf[i] = make_int2(c4.y, u1); }
            if (u2 > 0) { int i = atomicAdd(&lcnt, 1); if (i < 512) buf[i] = make_int2(c4.z, u2); }
            if (u3 > 0) { int i = atomicAdd(&lcnt, 1); if (i < 512) buf[i] = make_int2(c4.w, u3); }
        } else {
            for (int e = base; e < e1; ++e) {
                int u = ucnt[row[e]];
                if (u > 0) { int i = atomicAdd(&lcnt, 1); if (i < 512) buf[i] = make_int2(col[e], u); }
            }
        }
    }
    __syncthreads();
    if (threadIdx.x == 0) {
        int c = lcnt; c = c < 512 ? c : 512;
        lbase = atomicAdd(n_sel, c);
    }
    __syncthreads();
    int c = lcnt; c = c < 512 ? c : 512;
    int b = lbase;
    for (int i = threadIdx.x; i < c; i += 256) {
        int o = b + i;
        if (o < SEL_CAP) { sel_col[o] = buf[i].x; sel_w[o] = (float)buf[i].y; }
    }
}

// ---- stage 3: placement -- pure LDS-staged slice sort, burst write-out ---

__global__ __launch_bounds__(512) void place_kernel(
        const int* __restrict__ row, const int* __restrict__ col,
        const unsigned char* __restrict__ rkR, const unsigned char* __restrict__ rkC,
        const unsigned short* __restrict__ cntR, const unsigned short* __restrict__ cntC,
        const unsigned short* __restrict__ offR, const unsigned short* __restrict__ offC,
        const int* __restrict__ baseR, const int* __restrict__ baseC,
        unsigned short* __restrict__ midR, unsigned int* __restrict__ midC) {
    __shared__ int lofC[NBUK], lofR[NBUK], posC[NBUK], posR[NBUK];
    __shared__ int cCl[NBUK], cRl[NBUK];
    __shared__ int scan_tmp[512];
    __shared__ unsigned int   stC[EPS];
    __shared__ unsigned short stR[EPS];
    int blk = blockIdx.x, t = threadIdx.x;
    if (t < NBUK) {
        cCl[t] = (int)cntC[(size_t)blk * NBUK + t];
        cRl[t] = (int)cntR[(size_t)blk * NBUK + t];
        posC[t] = baseC[t] + (int)offC[(size_t)blk * NBUK + t];
        posR[t] = baseR[t] + (int)offR[(size_t)blk * NBUK + t];
    }
    __syncthreads();
    scan_tmp[t] = (t < NBUK) ? cCl[t] : 0;
    __syncthreads();
    for (int o = 1; o < 512; o <<= 1) {
        int v = (t >= o) ? scan_tmp[t - o] : 0;
        __syncthreads();
        scan_tmp[t] += v;
        __syncthreads();
    }
    if (t < NBUK) lofC[t] = scan_tmp[t] - cCl[t];
    __syncthreads();
    scan_tmp[t] = (t < NBUK) ? cRl[t] : 0;
    __syncthreads();
    for (int o = 1; o < 512; o <<= 1) {
        int v = (t >= o) ? scan_tmp[t - o] : 0;
        __syncthreads();
        scan_tmp[t] += v;
        __syncthreads();
    }
    if (t < NBUK) lofR[t] = scan_tmp[t] - cRl[t];
    __syncthreads();
    int e0 = blk * EPS;
    int e1 = e0 + EPS; if (e1 > NEDGE) e1 = NEDGE;
    for (int base = e0 + t * 4; base < e1; base += 2048) {
        if (base + 4 <= e1) {
            int4 r4 = *(const int4*)(row + base);
            int4 c4 = *(const int4*)(col + base);
            uchar4 kr = *(const uchar4*)(rkR + base);
            uchar4 kc = *(const uchar4*)(rkC + base);
            stC[lofC[c4.x >> 9] + (int)kc.x] = ((unsigned int)(c4.x & 511) << 18) | (unsigned int)r4.x;
            stC[lofC[c4.y >> 9] + (int)kc.y] = ((unsigned int)(c4.y & 511) << 18) | (unsigned int)r4.y;
            stC[lofC[c4.z >> 9] + (int)kc.z] = ((unsigned int)(c4.z & 511) << 18) | (unsigned int)r4.z;
            stC[lofC[c4.w >> 9] + (int)kc.w] = ((unsigned int)(c4.w & 511) << 18) | (unsigned int)r4.w;
            stR[lofR[r4.x >> 9] + (int)kr.x] = (unsigned short)(r4.x & 511);
            stR[lofR[r4.y >> 9] + (int)kr.y] = (unsigned short)(r4.y & 511);
            stR[lofR[r4.z >> 9] + (int)kr.z] = (unsigned short)(r4.z & 511);
            stR[lofR[r4.w >> 9] + (int)kr.w] = (unsigned short)(r4.w & 511);
        } else {
            for (int e = base; e < e1; ++e) {
                int r = row[e], c = col[e];
                stC[lofC[c >> 9] + (int)rkC[e]] = ((unsigned int)(c & 511) << 18) | (unsigned int)r;
                stR[lofR[r >> 9] + (int)rkR[e]] = (unsigned short)(r & 511);
            }
        }
    }
    __syncthreads();
    int wave = t >> 6, lane = t & 63;
    for (int b = wave; b < NBUK; b += 8) {
        int n = cCl[b], lo = lofC[b], dst = posC[b];
        for (int i = lane; i < n; i += 64) midC[dst + i] = stC[lo + i];
        n = cRl[b]; lo = lofR[b]; dst = posR[b];
        for (int i = lane; i < n; i += 64) midR[dst + i] = stR[lo + i];
    }
}

// ---- stage 4a: per col-bucket: count -> scan -> rptr + permute to CSR ----

__global__ __launch_bounds__(1024) void bfinal_col_kernel(
        const unsigned int* __restrict__ midC, const int* __restrict__ baseC,
        int* __restrict__ rptr, int* __restrict__ src_sorted) {
    __shared__ int cnt[512], sm[512], cur[512];
    int b = blockIdx.x;
    int s0 = baseC[b], s1 = baseC[b + 1];
    int t = threadIdx.x;
    if (t < 512) cnt[t] = 0;
    __syncthreads();
    for (int i = s0 + t; i < s1; i += 1024) atomicAdd(&cnt[midC[i] >> 18], 1);
    __syncthreads();
    if (t < 512) sm[t] = cnt[t];
    __syncthreads();
    for (int off = 1; off < 512; off <<= 1) {
        int v = 0;
        if (t < 512 && t >= off) v = sm[t - off];
        __syncthreads();
        if (t < 512) sm[t] += v;
        __syncthreads();
    }
    if (t < 512) {
        int excl = s0 + sm[t] - cnt[t];
        int n = b * 512 + t;
        if (n < NNODES) rptr[n] = excl;
        cur[t] = excl;
    }
    if (b == NBUK - 1 && t == 0) rptr[NNODES] = s1;   // == NEDGE
    __syncthreads();
    for (int i = s0 + t; i < s1; i += 1024) {
        unsigned int v = midC[i];
        int dst = atomicAdd(&cur[v >> 18], 1);
        src_sorted[dst] = (int)(v & 0x3FFFFu);
    }
}

// ---- stage 4b: per row-bucket: count -> dinv / dinv2 ---------------------

__global__ __launch_bounds__(1024) void bfinal_row_kernel(
        const unsigned short* __restrict__ midR, const int* __restrict__ baseR,
        float* __restrict__ dinv, float* __restrict__ dinv2) {
    __shared__ int cnt[512];
    int b = blockIdx.x;
    int s0 = baseR[b], s1 = baseR[b + 1];
    int t = threadIdx.x;
    if (t < 512) cnt[t] = 0;
    __syncthreads();
    for (int i = s0 + t; i < s1; i += 1024) atomicAdd(&cnt[midR[i]], 1);
    __syncthreads();
    if (t < 512) {
        int n = b * 512 + t;
        if (n < NNODES) {
            float d = fmaxf((float)cnt[t], 1.0f);
            dinv[n] = rsqrtf(d);
            dinv2[n] = 1.0f / d;
        }
    }
}

// ---- f32 embed -> bf16 y0 = dinv * x0 -----------------------------------

__global__ void cvt_kernel(const float4* __restrict__ src, uint2* __restrict__ dst,
                           const float* __restrict__ dinv) {
    int t = blockIdx.x * blockDim.x + threadIdx.x;   // one uint2 = 4 bf16
    if (t >= NNODES * 16) return;
    float d = dinv[t >> 4];
    float4 v = src[t];
    unsigned int w0 = (unsigned int)f2bf(v.x * d) | ((unsigned int)f2bf(v.y * d) << 16);
    unsigned int w1 = (unsigned int)f2bf(v.z * d) | ((unsigned int)f2bf(v.w * d) << 16);
    dst[t] = make_uint2(w0, w1);
}

// ---- propagation in y-space: out[c] = scale[c] * sum over in-edges y[r] --

__global__ void prop_kernel(const uint2* __restrict__ x_in, uint2* __restrict__ x_out,
                            const int* __restrict__ ptr, const int* __restrict__ src,
                            const float* __restrict__ scale) {
    int gid  = blockIdx.x * blockDim.x + threadIdx.x;
    int node = gid >> 4;       // 16 lanes per node
    int sl   = gid & 15;       // lane's 4-dim slot within the row
    if (node >= NNODES) return;
    int s = ptr[node], e = ptr[node + 1];
    float a0 = 0.f, a1 = 0.f, a2 = 0.f, a3 = 0.f;
    int i = s;
    for (; i + 4 <= e; i += 4) {
        int s0 = src[i], s1 = src[i + 1], s2 = src[i + 2], s3 = src[i + 3];
        uint2 w0 = x_in[s0 * 16 + sl];
        uint2 w1 = x_in[s1 * 16 + sl];
        uint2 w2 = x_in[s2 * 16 + sl];
        uint2 w3 = x_in[s3 * 16 + sl];
        a0 += __uint_as_float(w0.x << 16); a1 += __uint_as_float(w0.x & 0xffff0000u);
        a2 += __uint_as_float(w0.y << 16); a3 += __uint_as_float(w0.y & 0xffff0000u);
        a0 += __uint_as_float(w1.x << 16); a1 += __uint_as_float(w1.x & 0xffff0000u);
        a2 += __uint_as_float(w1.y << 16); a3 += __uint_as_float(w1.y & 0xffff0000u);
        a0 += __uint_as_float(w2.x << 16); a1 += __uint_as_float(w2.x & 0xffff0000u);
        a2 += __uint_as_float(w2.y << 16); a3 += __uint_as_float(w2.y & 0xffff0000u);
        a0 += __uint_as_float(w3.x << 16); a1 += __uint_as_float(w3.x & 0xffff0000u);
        a2 += __uint_as_float(w3.y << 16); a3 += __uint_as_float(w3.y & 0xffff0000u);
    }
    for (; i < e; ++i) {
        uint2 w0 = x_in[src[i] * 16 + sl];
        a0 += __uint_as_float(w0.x << 16); a1 += __uint_as_float(w0.x & 0xffff0000u);
        a2 += __uint_as_float(w0.y << 16); a3 += __uint_as_float(w0.y & 0xffff0000u);
    }
    float sc = scale[node];
    unsigned int o0 = (unsigned int)f2bf(a0 * sc) | ((unsigned int)f2bf(a1 * sc) << 16);
    unsigned int o1 = (unsigned int)f2bf(a2 * sc) | ((unsigned int)f2bf(a3 * sc) << 16);
    x_out[node * 16 + sl] = make_uint2(o0, o1);
}

// ---- batch / softmax part (x is bf16) -----------------------------------

__global__ void ucnt_kernel(const int* __restrict__ users, int* __restrict__ ucnt) {
    int b = blockIdx.x * blockDim.x + threadIdx.x;
    if (b < BATCH) atomicAdd(&ucnt[users[b]], 1);
}

__global__ void ctx_kernel(const unsigned short* __restrict__ x, const int* __restrict__ users,
                           float* __restrict__ ctx) {
    __shared__ float sm[256];
    int lane = threadIdx.x & 63, wl = threadIdx.x >> 6;
    float acc = 0.0f;
    for (int b = wl; b < BATCH; b += 4) acc += bf2f(x[users[b] * DIM + lane]);
    sm[threadIdx.x] = acc; __syncthreads();
    if (wl == 0)
        ctx[lane] = (sm[lane] + sm[64 + lane] + sm[128 + lane] + sm[192 + lane]) * (1.0f / BATCH);
}

__global__ void logit_kernel(const unsigned short* __restrict__ x, const float* __restrict__ ctx,
                             const int* __restrict__ sel_col, const int* __restrict__ n_sel_p,
                             float* __restrict__ sel_logit, float* __restrict__ blk_max) {
    __shared__ float sm[4];
    int lane = threadIdx.x & 63, wl = threadIdx.x >> 6;
    int n = *n_sel_p; if (n > SEL_CAP) n = SEL_CAP;
    float c = ctx[lane];
    float bmax = -FLT_MAX;
    int stride = gridDim.x * 4;
    for (int idx = blockIdx.x * 4 + wl; idx < n; idx += stride) {
        int node = sel_col[idx];
        float v = bf2f(x[node * DIM + lane]) * c;
        v = wave_sum64(v);
        if (lane == 0) sel_logit[idx] = v;
        bmax = fmaxf(bmax, v);
    }
    if (lane == 0) sm[wl] = bmax;
    __syncthreads();
    if (threadIdx.x == 0)
        blk_max[blockIdx.x] = fmaxf(fmaxf(sm[0], sm[1]), fmaxf(sm[2], sm[3]));
}

__global__ void max_kernel(const float* __restrict__ blk_max, float* __restrict__ mx) {
    __shared__ float sm[256];
    int t = threadIdx.x;
    float m = fmaxf(blk_max[t], blk_max[t + 256]);
    sm[t] = m; __syncthreads();
    for (int off = 128; off > 0; off >>= 1) {
        if (t < off) sm[t] = fmaxf(sm[t], sm[t + off]);
        __syncthreads();
    }
    if (t == 0) *mx = sm[0];
}

__global__ void accum_kernel(const unsigned short* __restrict__ x, const int* __restrict__ sel_col,
                             const float* __restrict__ sel_w, const float* __restrict__ sel_logit,
                             const int* __restrict__ n_sel_p, const float* __restrict__ mx_p,
                             float* __restrict__ S, float* __restrict__ zp) {
    __shared__ float smS[4 * 64];
    __shared__ float smZ[4];
    int lane = threadIdx.x & 63, wl = threadIdx.x >> 6;
    int n = *n_sel_p; if (n > SEL_CAP) n = SEL_CAP;
    float mx = *mx_p;
    float accS = 0.0f, accZ = 0.0f;
    int stride = gridDim.x * 4;
    for (int idx = blockIdx.x * 4 + wl; idx < n; idx += stride) {
        int node = sel_col[idx];
        float w = sel_w[idx] * __expf(sel_logit[idx] - mx);
        accS = fmaf(w, bf2f(x[node * DIM + lane]), accS);
        accZ += w;
    }
    smS[wl * 64 + lane] = accS;
    if (lane == 0) smZ[wl] = accZ;
    __syncthreads();
    if (wl == 0) {
        float s = smS[lane] + smS[64 + lane] + smS[128 + lane] + smS[192 + lane];
        atomicAdd(&S[lane], s);
    }
    if (threadIdx.x == 0) atomicAdd(zp, smZ[0] + smZ[1] + smZ[2] + smZ[3]);
}

__global__ void score_kernel(const unsigned short* __restrict__ x, const int* __restrict__ users,
                             const int* __restrict__ items, const float* __restrict__ S,
                             const float* __restrict__ zp, float* __restrict__ out) {
    int gid = blockIdx.x * blockDim.x + threadIdx.x;
    int b = gid >> 6, lane = gid & 63;
    if (b >= BATCH) return;
    float z = fmaxf(*zp, 1e-12f);
    float na = S[lane] / z;
    int u = users[b], it = items[b] + NUM_USERS;
    float v = bf2f(x[u * DIM + lane]) * (bf2f(x[it * DIM + lane]) + na);
    v = wave_sum64(v);
    if (lane == 0) out[b] = 1.0f / (1.0f + __expf(-v));
}

// ---- launch -------------------------------------------------------------

extern "C" void kernel_launch(void* const* d_in, const int* in_sizes, int n_in,
                              void* d_out, int out_size, void* d_ws, size_t ws_size,
                              hipStream_t stream) {
    const float* embed = (const float*)d_in[0];
    const int*   edge  = (const int*)d_in[1];
    const int*   row   = edge;
    const int*   col   = edge + NEDGE;
    const int*   users = (const int*)d_in[2];
    const int*   items = (const int*)d_in[3];
    float*       out   = (float*)d_out;
    char*        ws    = (char*)d_ws;

    size_t off = 0;
    auto A = [&](size_t bytes) { size_t o = off; off += (bytes + 255) & ~(size_t)255; return o; };
    // big region: midC (8 MB) + midR (4 MB) during build; xa (19.2 MB) after
    size_t o_big   = A((size_t)NNODES * DIM * 2);      // 19.2 MB
    size_t o_xb    = A((size_t)NNODES * DIM * 2);      // 19.2 MB
    size_t o_src   = A((size_t)NEDGE * 4);             // 8 MB, alive thru prop
    size_t o_rkR   = A((size_t)SLICES * EPS);          // 2 MB
    size_t o_rkC   = A((size_t)SLICES * EPS);          // 2 MB
    size_t o_cntR  = A((size_t)SLICES * NBUK * 2);     // 300 KB
    size_t o_cntC  = A((size_t)SLICES * NBUK * 2);
    size_t o_offR  = A((size_t)SLICES * NBUK * 2);
    size_t o_offC  = A((size_t)SLICES * NBUK * 2);
    size_t o_tot   = A((size_t)2 * NBUK * 4);
    size_t o_baseR = A((size_t)(NBUK + 1) * 4);
    size_t o_baseC = A((size_t)(NBUK + 1) * 4);
    size_t o_selc  = A((size_t)SEL_CAP * 4);
    size_t o_selw  = A((size_t)SEL_CAP * 4);
    size_t o_sell  = A((size_t)SEL_CAP * 4);
    size_t o_zero  = off;                              // ---- zeroed block ----
    size_t o_ucnt  = A((size_t)NNODES * 4);
    size_t o_misc  = A(1024);                          // n_sel@0, mx@4, z@8, S@256
    size_t zero_bytes = off - o_zero;                  // ---- end zero -------
    size_t o_dinv  = A((size_t)NNODES * 4);
    size_t o_dinv2 = A((size_t)NNODES * 4);
    size_t o_rptr  = A((size_t)(NNODES + 1) * 4);
    size_t o_bmax  = A((size_t)LOGIT_BLOCKS * 4);
    size_t o_ctx   = A(256);

    unsigned int*   midC = (unsigned int*)(ws + o_big);                // 8 MB
    unsigned short* midR = (unsigned short*)(ws + o_big + (size_t)NEDGE * 4);  // 4 MB
    unsigned short* xa   = (unsigned short*)(ws + o_big);              // overlay after build
    unsigned short* xb   = (unsigned short*)(ws + o_xb);
    int*   srcS  = (int*)(ws + o_src);
    unsigned char* rkR = (unsigned char*)(ws + o_rkR);
    unsigned char* rkC = (unsigned char*)(ws + o_rkC);
    unsigned short* cntR = (unsigned short*)(ws + o_cntR);
    unsigned short* cntC = (unsigned short*)(ws + o_cntC);
    unsigned short* offR = (unsigned short*)(ws + o_offR);
    unsigned short* offC = (unsigned short*)(ws + o_offC);
    int*   totRC = (int*)(ws + o_tot);
    int*   baseR = (int*)(ws + o_baseR);
    int*   baseC = (int*)(ws + o_baseC);
    int*   selc  = (int*)(ws + o_selc);
    float* selw  = (float*)(ws + o_selw);
    float* sell  = (float*)(ws + o_sell);
    int*   ucnt  = (int*)(ws + o_ucnt);
    int*   nsel  = (int*)(ws + o_misc);
    float* mx    = (float*)(ws + o_misc + 4);
    float* zp    = (float*)(ws + o_misc + 8);
    float* S     = (float*)(ws + o_misc + 256);
    float* dinv  = (float*)(ws + o_dinv);
    float* dinv2 = (float*)(ws + o_dinv2);
    int*   rptr  = (int*)(ws + o_rptr);
    float* bmax  = (float*)(ws + o_bmax);
    float* ctx   = (float*)(ws + o_ctx);

    hipMemsetAsync(ws + o_zero, 0, zero_bytes, stream);

    ucnt_kernel<<<(BATCH + 255) / 256, 256, 0, stream>>>(users, ucnt);

    // atomic-free CSR build
    bhist_kernel<<<SLICES, 512, 0, stream>>>(row, col, cntR, cntC, rkR, rkC);
    bprefix1_kernel<<<2 * NBUK, 512, 0, stream>>>(cntR, cntC, offR, offC, totRC);
    bprefix2_kernel<<<2, 512, 0, stream>>>(totRC, baseR, baseC);
    // standalone low-atomic selection (isolated from placement)
    select_kernel<<<SELB, 256, 0, stream>>>(row, col, ucnt, nsel, selc, selw);
    place_kernel<<<SLICES, 512, 0, stream>>>(row, col, rkR, rkC, cntR, cntC,
                                             offR, offC, baseR, baseC, midR, midC);
    bfinal_col_kernel<<<NBUK, 1024, 0, stream>>>(midC, baseC, rptr, srcS);
    bfinal_row_kernel<<<NBUK, 1024, 0, stream>>>(midR, baseR, dinv, dinv2);

    // y0 = bf16(dinv*embed); layers: y->y (dinv2), y->y (dinv2), y->x (dinv)
    cvt_kernel<<<(NNODES * 16 + 255) / 256, 256, 0, stream>>>((const float4*)embed, (uint2*)xa, dinv);
    int prop_blocks = (NNODES * 16 + 255) / 256;
    prop_kernel<<<prop_blocks, 256, 0, stream>>>((const uint2*)xa, (uint2*)xb, rptr, srcS, dinv2);
    prop_kernel<<<prop_blocks, 256, 0, stream>>>((const uint2*)xb, (uint2*)xa, rptr, srcS, dinv2);
    prop_kernel<<<prop_blocks, 256, 0, stream>>>((const uint2*)xa, (uint2*)xb, rptr, srcS, dinv);
    // final x lives in xb

    // batch softmax aggregation over selected edges
    ctx_kernel<<<1, 256, 0, stream>>>(xb, users, ctx);
    logit_kernel<<<LOGIT_BLOCKS, 256, 0, stream>>>(xb, ctx, selc, nsel, sell, bmax);
    max_kernel<<<1, 256, 0, stream>>>(bmax, mx);
    accum_kernel<<<LOGIT_BLOCKS, 256, 0, stream>>>(xb, selc, selw, sell, nsel, mx, S, zp);

    // final scores
    score_kernel<<<(BATCH * 64 + 255) / 256, 256, 0, stream>>>(xb, users, items, S, zp, out);
}

// Round 13
// 341.203 us; speedup vs baseline: 1.6829x; 1.2954x over previous
//
#include <hip/hip_runtime.h>
#include <float.h>
#include <math.h>

#define NUM_USERS 100000
#define NUM_ITEMS 50000
#define NNODES    150000
#define DIM       64
#define NEDGE     2000000
#define BATCH     1024
#define SEL_CAP   (1 << 18)
#define LOGIT_BLOCKS 512

#define SLICES   512                    // edge slices (= threads in bprefix1 scan)
#define EPS      3908                   // ceil(NEDGE/SLICES) rounded to x4
#define NBUK     293                    // buckets of 512 nodes (293*512=150016)
#define SELB     977                    // ceil(NEDGE/2048) selection blocks

__device__ __forceinline__ float wave_sum64(float v) {
    #pragma unroll
    for (int off = 32; off > 0; off >>= 1) v += __shfl_xor(v, off, 64);
    return v;
}

__device__ __forceinline__ float bf2f(unsigned short s) {
    return __uint_as_float(((unsigned int)s) << 16);
}
__device__ __forceinline__ unsigned short f2bf(float f) {   // RNE
    unsigned int u = __float_as_uint(f);
    return (unsigned short)((u + 0x7fffu + ((u >> 16) & 1u)) >> 16);
}

// ---- stage 1: per-slice 293-bucket histograms + u8 rank capture ---------

__global__ __launch_bounds__(512) void bhist_kernel(
        const int* __restrict__ row, const int* __restrict__ col,
        unsigned short* __restrict__ cntR, unsigned short* __restrict__ cntC,
        unsigned char* __restrict__ rkR, unsigned char* __restrict__ rkC) {
    __shared__ unsigned int hr[NBUK], hc[NBUK];
    int blk = blockIdx.x, t = threadIdx.x;
    for (int i = t; i < NBUK; i += 512) { hr[i] = 0; hc[i] = 0; }
    __syncthreads();
    int e0 = blk * EPS;
    int e1 = e0 + EPS; if (e1 > NEDGE) e1 = NEDGE;
    for (int base = e0 + t * 4; base < e1; base += 2048) {
        if (base + 4 <= e1) {
            int4 r4 = *(const int4*)(row + base);
            int4 c4 = *(const int4*)(col + base);
            uchar4 a, b;
            a.x = (unsigned char)atomicAdd(&hr[r4.x >> 9], 1u);
            a.y = (unsigned char)atomicAdd(&hr[r4.y >> 9], 1u);
            a.z = (unsigned char)atomicAdd(&hr[r4.z >> 9], 1u);
            a.w = (unsigned char)atomicAdd(&hr[r4.w >> 9], 1u);
            b.x = (unsigned char)atomicAdd(&hc[c4.x >> 9], 1u);
            b.y = (unsigned char)atomicAdd(&hc[c4.y >> 9], 1u);
            b.z = (unsigned char)atomicAdd(&hc[c4.z >> 9], 1u);
            b.w = (unsigned char)atomicAdd(&hc[c4.w >> 9], 1u);
            *(uchar4*)(rkR + base) = a;
            *(uchar4*)(rkC + base) = b;
        } else {
            for (int e = base; e < e1; ++e) {
                rkR[e] = (unsigned char)atomicAdd(&hr[row[e] >> 9], 1u);
                rkC[e] = (unsigned char)atomicAdd(&hc[col[e] >> 9], 1u);
            }
        }
    }
    __syncthreads();
    for (int i = t; i < NBUK; i += 512) {
        cntR[(size_t)blk * NBUK + i] = (unsigned short)hr[i];
        cntC[(size_t)blk * NBUK + i] = (unsigned short)hc[i];
    }
}

// ---- stage 2: parallel per-bucket prefix over slices ---------------------

__global__ __launch_bounds__(512) void bprefix1_kernel(
        const unsigned short* __restrict__ cntR, const unsigned short* __restrict__ cntC,
        unsigned short* __restrict__ offR, unsigned short* __restrict__ offC,
        int* __restrict__ totRC) {
    int side = blockIdx.x / NBUK;
    int b = blockIdx.x - side * NBUK;
    const unsigned short* cnt = side ? cntC : cntR;
    unsigned short* off = side ? offC : offR;
    __shared__ int sm[512];
    int t = threadIdx.x;
    int v = (int)cnt[(size_t)t * NBUK + b];
    sm[t] = v;
    __syncthreads();
    for (int o = 1; o < 512; o <<= 1) {
        int x = (t >= o) ? sm[t - o] : 0;
        __syncthreads();
        sm[t] += x;
        __syncthreads();
    }
    off[(size_t)t * NBUK + b] = (unsigned short)(sm[t] - v);
    if (t == 511) totRC[side * NBUK + b] = sm[511];
}

__global__ __launch_bounds__(512) void bprefix2_kernel(
        const int* __restrict__ totRC, int* __restrict__ baseR, int* __restrict__ baseC) {
    const int* tot = totRC + blockIdx.x * NBUK;
    int* base = blockIdx.x ? baseC : baseR;
    __shared__ int sm[512];
    int t = threadIdx.x;
    int v = (t < NBUK) ? tot[t] : 0;
    sm[t] = v;
    __syncthreads();
    for (int o = 1; o < 512; o <<= 1) {
        int x = (t >= o) ? sm[t - o] : 0;
        __syncthreads();
        sm[t] += x;
        __syncthreads();
    }
    if (t < NBUK) base[t] = sm[t] - v;
    if (t == NBUK - 1) base[NBUK] = sm[t];     // == NEDGE
}

// ---- batch-edge selection (standalone, low-atomic) -----------------------

__global__ __launch_bounds__(256) void select_kernel(
        const int* __restrict__ row, const int* __restrict__ col,
        const int* __restrict__ ucnt,
        int* __restrict__ n_sel, int* __restrict__ sel_col, float* __restrict__ sel_w) {
    __shared__ int lcnt, lbase;
    __shared__ int2 buf[512];
    if (threadIdx.x == 0) lcnt = 0;
    __syncthreads();
    int e0 = blockIdx.x * 2048;
    int e1 = e0 + 2048; if (e1 > NEDGE) e1 = NEDGE;
    for (int base = e0 + (int)threadIdx.x * 4; base < e1; base += 1024) {
        if (base + 4 <= e1) {
            int4 r4 = *(const int4*)(row + base);
            int4 c4 = *(const int4*)(col + base);
            int u0 = ucnt[r4.x], u1 = ucnt[r4.y], u2 = ucnt[r4.z], u3 = ucnt[r4.w];
            if (u0 > 0) { int i = atomicAdd(&lcnt, 1); if (i < 512) buf[i] = make_int2(c4.x, u0); }
            if (u1 > 0) { int i = atomicAdd(&lcnt, 1); if (i < 512) buf[i] = make_int2(c4.y, u1); }
            if (u2 > 0) { int i = atomicAdd(&lcnt, 1); if (i < 512) buf[i] = make_int2(c4.z, u2); }
            if (u3 > 0) { int i = atomicAdd(&lcnt, 1); if (i < 512) buf[i] = make_int2(c4.w, u3); }
        } else {
            for (int e = base; e < e1; ++e) {
                int u = ucnt[row[e]];
                if (u > 0) { int i = atomicAdd(&lcnt, 1); if (i < 512) buf[i] = make_int2(col[e], u); }
            }
        }
    }
    __syncthreads();
    if (threadIdx.x == 0) {
        int c = lcnt; c = c < 512 ? c : 512;
        lbase = atomicAdd(n_sel, c);
    }
    __syncthreads();
    int c = lcnt; c = c < 512 ? c : 512;
    int b = lbase;
    for (int i = threadIdx.x; i < c; i += 256) {
        int o = b + i;
        if (o < SEL_CAP) { sel_col[o] = buf[i].x; sel_w[o] = (float)buf[i].y; }
    }
}

// ---- stage 3: placement -- pure LDS-staged slice sort, burst write-out ---

__global__ __launch_bounds__(512) void place_kernel(
        const int* __restrict__ row, const int* __restrict__ col,
        const unsigned char* __restrict__ rkR, const unsigned char* __restrict__ rkC,
        const unsigned short* __restrict__ cntR, const unsigned short* __restrict__ cntC,
        const unsigned short* __restrict__ offR, const unsigned short* __restrict__ offC,
        const int* __restrict__ baseR, const int* __restrict__ baseC,
        unsigned short* __restrict__ midR, unsigned int* __restrict__ midC) {
    __shared__ int lofC[NBUK], lofR[NBUK], posC[NBUK], posR[NBUK];
    __shared__ int cCl[NBUK], cRl[NBUK];
    __shared__ int scan_tmp[512];
    __shared__ unsigned int   stC[EPS];
    __shared__ unsigned short stR[EPS];
    int blk = blockIdx.x, t = threadIdx.x;
    if (t < NBUK) {
        cCl[t] = (int)cntC[(size_t)blk * NBUK + t];
        cRl[t] = (int)cntR[(size_t)blk * NBUK + t];
        posC[t] = baseC[t] + (int)offC[(size_t)blk * NBUK + t];
        posR[t] = baseR[t] + (int)offR[(size_t)blk * NBUK + t];
    }
    __syncthreads();
    scan_tmp[t] = (t < NBUK) ? cCl[t] : 0;
    __syncthreads();
    for (int o = 1; o < 512; o <<= 1) {
        int v = (t >= o) ? scan_tmp[t - o] : 0;
        __syncthreads();
        scan_tmp[t] += v;
        __syncthreads();
    }
    if (t < NBUK) lofC[t] = scan_tmp[t] - cCl[t];
    __syncthreads();
    scan_tmp[t] = (t < NBUK) ? cRl[t] : 0;
    __syncthreads();
    for (int o = 1; o < 512; o <<= 1) {
        int v = (t >= o) ? scan_tmp[t - o] : 0;
        __syncthreads();
        scan_tmp[t] += v;
        __syncthreads();
    }
    if (t < NBUK) lofR[t] = scan_tmp[t] - cRl[t];
    __syncthreads();
    int e0 = blk * EPS;
    int e1 = e0 + EPS; if (e1 > NEDGE) e1 = NEDGE;
    for (int base = e0 + t * 4; base < e1; base += 2048) {
        if (base + 4 <= e1) {
            int4 r4 = *(const int4*)(row + base);
            int4 c4 = *(const int4*)(col + base);
            uchar4 kr = *(const uchar4*)(rkR + base);
            uchar4 kc = *(const uchar4*)(rkC + base);
            stC[lofC[c4.x >> 9] + (int)kc.x] = ((unsigned int)(c4.x & 511) << 18) | (unsigned int)r4.x;
            stC[lofC[c4.y >> 9] + (int)kc.y] = ((unsigned int)(c4.y & 511) << 18) | (unsigned int)r4.y;
            stC[lofC[c4.z >> 9] + (int)kc.z] = ((unsigned int)(c4.z & 511) << 18) | (unsigned int)r4.z;
            stC[lofC[c4.w >> 9] + (int)kc.w] = ((unsigned int)(c4.w & 511) << 18) | (unsigned int)r4.w;
            stR[lofR[r4.x >> 9] + (int)kr.x] = (unsigned short)(r4.x & 511);
            stR[lofR[r4.y >> 9] + (int)kr.y] = (unsigned short)(r4.y & 511);
            stR[lofR[r4.z >> 9] + (int)kr.z] = (unsigned short)(r4.z & 511);
            stR[lofR[r4.w >> 9] + (int)kr.w] = (unsigned short)(r4.w & 511);
        } else {
            for (int e = base; e < e1; ++e) {
                int r = row[e], c = col[e];
                stC[lofC[c >> 9] + (int)rkC[e]] = ((unsigned int)(c & 511) << 18) | (unsigned int)r;
                stR[lofR[r >> 9] + (int)rkR[e]] = (unsigned short)(r & 511);
            }
        }
    }
    __syncthreads();
    int wave = t >> 6, lane = t & 63;
    for (int b = wave; b < NBUK; b += 8) {
        int n = cCl[b], lo = lofC[b], dst = posC[b];
        for (int i = lane; i < n; i += 64) midC[dst + i] = stC[lo + i];
        n = cRl[b]; lo = lofR[b]; dst = posR[b];
        for (int i = lane; i < n; i += 64) midR[dst + i] = stR[lo + i];
    }
}

// ---- stage 4a: per col-bucket: count -> scan -> rptr + permute to CSR ----

__global__ __launch_bounds__(1024) void bfinal_col_kernel(
        const unsigned int* __restrict__ midC, const int* __restrict__ baseC,
        int* __restrict__ rptr, int* __restrict__ src_sorted) {
    __shared__ int cnt[512], sm[512], cur[512];
    int b = blockIdx.x;
    int s0 = baseC[b], s1 = baseC[b + 1];
    int t = threadIdx.x;
    if (t < 512) cnt[t] = 0;
    __syncthreads();
    for (int i = s0 + t; i < s1; i += 1024) atomicAdd(&cnt[midC[i] >> 18], 1);
    __syncthreads();
    if (t < 512) sm[t] = cnt[t];
    __syncthreads();
    for (int off = 1; off < 512; off <<= 1) {
        int v = 0;
        if (t < 512 && t >= off) v = sm[t - off];
        __syncthreads();
        if (t < 512) sm[t] += v;
        __syncthreads();
    }
    if (t < 512) {
        int excl = s0 + sm[t] - cnt[t];
        int n = b * 512 + t;
        if (n < NNODES) rptr[n] = excl;
        cur[t] = excl;
    }
    if (b == NBUK - 1 && t == 0) rptr[NNODES] = s1;   // == NEDGE
    __syncthreads();
    for (int i = s0 + t; i < s1; i += 1024) {
        unsigned int v = midC[i];
        int dst = atomicAdd(&cur[v >> 18], 1);
        src_sorted[dst] = (int)(v & 0x3FFFFu);
    }
}

// ---- stage 4b: per row-bucket: count -> dinv / dinv2 ---------------------

__global__ __launch_bounds__(1024) void bfinal_row_kernel(
        const unsigned short* __restrict__ midR, const int* __restrict__ baseR,
        float* __restrict__ dinv, float* __restrict__ dinv2) {
    __shared__ int cnt[512];
    int b = blockIdx.x;
    int s0 = baseR[b], s1 = baseR[b + 1];
    int t = threadIdx.x;
    if (t < 512) cnt[t] = 0;
    __syncthreads();
    for (int i = s0 + t; i < s1; i += 1024) atomicAdd(&cnt[midR[i]], 1);
    __syncthreads();
    if (t < 512) {
        int n = b * 512 + t;
        if (n < NNODES) {
            float d = fmaxf((float)cnt[t], 1.0f);
            dinv[n] = rsqrtf(d);
            dinv2[n] = 1.0f / d;
        }
    }
}

// ---- f32 embed -> bf16 y0 = dinv * x0 -----------------------------------

__global__ void cvt_kernel(const float4* __restrict__ src, uint2* __restrict__ dst,
                           const float* __restrict__ dinv) {
    int t = blockIdx.x * blockDim.x + threadIdx.x;   // one uint2 = 4 bf16
    if (t >= NNODES * 16) return;
    float d = dinv[t >> 4];
    float4 v = src[t];
    unsigned int w0 = (unsigned int)f2bf(v.x * d) | ((unsigned int)f2bf(v.y * d) << 16);
    unsigned int w1 = (unsigned int)f2bf(v.z * d) | ((unsigned int)f2bf(v.w * d) << 16);
    dst[t] = make_uint2(w0, w1);
}

// ---- propagation in y-space: out[c] = scale[c] * sum over in-edges y[r] --

__global__ void prop_kernel(const uint2* __restrict__ x_in, uint2* __restrict__ x_out,
                            const int* __restrict__ ptr, const int* __restrict__ src,
                            const float* __restrict__ scale) {
    int gid  = blockIdx.x * blockDim.x + threadIdx.x;
    int node = gid >> 4;       // 16 lanes per node
    int sl   = gid & 15;       // lane's 4-dim slot within the row
    if (node >= NNODES) return;
    int s = ptr[node], e = ptr[node + 1];
    float a0 = 0.f, a1 = 0.f, a2 = 0.f, a3 = 0.f;
    int i = s;
    for (; i + 4 <= e; i += 4) {
        int s0 = src[i], s1 = src[i + 1], s2 = src[i + 2], s3 = src[i + 3];
        uint2 w0 = x_in[s0 * 16 + sl];
        uint2 w1 = x_in[s1 * 16 + sl];
        uint2 w2 = x_in[s2 * 16 + sl];
        uint2 w3 = x_in[s3 * 16 + sl];
        a0 += __uint_as_float(w0.x << 16); a1 += __uint_as_float(w0.x & 0xffff0000u);
        a2 += __uint_as_float(w0.y << 16); a3 += __uint_as_float(w0.y & 0xffff0000u);
        a0 += __uint_as_float(w1.x << 16); a1 += __uint_as_float(w1.x & 0xffff0000u);
        a2 += __uint_as_float(w1.y << 16); a3 += __uint_as_float(w1.y & 0xffff0000u);
        a0 += __uint_as_float(w2.x << 16); a1 += __uint_as_float(w2.x & 0xffff0000u);
        a2 += __uint_as_float(w2.y << 16); a3 += __uint_as_float(w2.y & 0xffff0000u);
        a0 += __uint_as_float(w3.x << 16); a1 += __uint_as_float(w3.x & 0xffff0000u);
        a2 += __uint_as_float(w3.y << 16); a3 += __uint_as_float(w3.y & 0xffff0000u);
    }
    for (; i < e; ++i) {
        uint2 w0 = x_in[src[i] * 16 + sl];
        a0 += __uint_as_float(w0.x << 16); a1 += __uint_as_float(w0.x & 0xffff0000u);
        a2 += __uint_as_float(w0.y << 16); a3 += __uint_as_float(w0.y & 0xffff0000u);
    }
    float sc = scale[node];
    unsigned int o0 = (unsigned int)f2bf(a0 * sc) | ((unsigned int)f2bf(a1 * sc) << 16);
    unsigned int o1 = (unsigned int)f2bf(a2 * sc) | ((unsigned int)f2bf(a3 * sc) << 16);
    x_out[node * 16 + sl] = make_uint2(o0, o1);
}

// ---- batch / softmax part (x is bf16) -----------------------------------

__global__ void ucnt_kernel(const int* __restrict__ users, int* __restrict__ ucnt) {
    int b = blockIdx.x * blockDim.x + threadIdx.x;
    if (b < BATCH) atomicAdd(&ucnt[users[b]], 1);
}

// ctx phase 1: 256 blocks x 4 waves; wave w of block b loads user row 4b+w.
__global__ __launch_bounds__(256) void ctx_part_kernel(
        const unsigned short* __restrict__ x, const int* __restrict__ users,
        float* __restrict__ partial) {
    __shared__ float sm[256];
    int lane = threadIdx.x & 63, wl = threadIdx.x >> 6;
    int b = blockIdx.x * 4 + wl;
    float v = (b < BATCH) ? bf2f(x[users[b] * DIM + lane]) : 0.0f;
    sm[threadIdx.x] = v;
    __syncthreads();
    if (wl == 0)
        partial[blockIdx.x * 64 + lane] =
            sm[lane] + sm[64 + lane] + sm[128 + lane] + sm[192 + lane];
}

// ctx phase 2: reduce 256 partials -> ctx (mean over BATCH)
__global__ __launch_bounds__(256) void ctx_reduce_kernel(
        const float* __restrict__ partial, float* __restrict__ ctx) {
    __shared__ float sm[256];
    int lane = threadIdx.x & 63, wl = threadIdx.x >> 6;
    float acc = 0.0f;
    for (int i = wl; i < 256; i += 4) acc += partial[i * 64 + lane];
    sm[threadIdx.x] = acc;
    __syncthreads();
    if (wl == 0)
        ctx[lane] = (sm[lane] + sm[64 + lane] + sm[128 + lane] + sm[192 + lane])
                    * (1.0f / BATCH);
}

__global__ void logit_kernel(const unsigned short* __restrict__ x, const float* __restrict__ ctx,
                             const int* __restrict__ sel_col, const int* __restrict__ n_sel_p,
                             float* __restrict__ sel_logit, float* __restrict__ blk_max) {
    __shared__ float sm[4];
    int lane = threadIdx.x & 63, wl = threadIdx.x >> 6;
    int n = *n_sel_p; if (n > SEL_CAP) n = SEL_CAP;
    float c = ctx[lane];
    float bmax = -FLT_MAX;
    int stride = gridDim.x * 4;
    for (int idx = blockIdx.x * 4 + wl; idx < n; idx += stride) {
        int node = sel_col[idx];
        float v = bf2f(x[node * DIM + lane]) * c;
        v = wave_sum64(v);
        if (lane == 0) sel_logit[idx] = v;
        bmax = fmaxf(bmax, v);
    }
    if (lane == 0) sm[wl] = bmax;
    __syncthreads();
    if (threadIdx.x == 0)
        blk_max[blockIdx.x] = fmaxf(fmaxf(sm[0], sm[1]), fmaxf(sm[2], sm[3]));
}

__global__ void max_kernel(const float* __restrict__ blk_max, float* __restrict__ mx) {
    __shared__ float sm[256];
    int t = threadIdx.x;
    float m = fmaxf(blk_max[t], blk_max[t + 256]);
    sm[t] = m; __syncthreads();
    for (int off = 128; off > 0; off >>= 1) {
        if (t < off) sm[t] = fmaxf(sm[t], sm[t + off]);
        __syncthreads();
    }
    if (t == 0) *mx = sm[0];
}

__global__ void accum_kernel(const unsigned short* __restrict__ x, const int* __restrict__ sel_col,
                             const float* __restrict__ sel_w, const float* __restrict__ sel_logit,
                             const int* __restrict__ n_sel_p, const float* __restrict__ mx_p,
                             float* __restrict__ S, float* __restrict__ zp) {
    __shared__ float smS[4 * 64];
    __shared__ float smZ[4];
    int lane = threadIdx.x & 63, wl = threadIdx.x >> 6;
    int n = *n_sel_p; if (n > SEL_CAP) n = SEL_CAP;
    float mx = *mx_p;
    float accS = 0.0f, accZ = 0.0f;
    int stride = gridDim.x * 4;
    for (int idx = blockIdx.x * 4 + wl; idx < n; idx += stride) {
        int node = sel_col[idx];
        float w = sel_w[idx] * __expf(sel_logit[idx] - mx);
        accS = fmaf(w, bf2f(x[node * DIM + lane]), accS);
        accZ += w;
    }
    smS[wl * 64 + lane] = accS;
    if (lane == 0) smZ[wl] = accZ;
    __syncthreads();
    if (wl == 0) {
        float s = smS[lane] + smS[64 + lane] + smS[128 + lane] + smS[192 + lane];
        atomicAdd(&S[lane], s);
    }
    if (threadIdx.x == 0) atomicAdd(zp, smZ[0] + smZ[1] + smZ[2] + smZ[3]);
}

__global__ void score_kernel(const unsigned short* __restrict__ x, const int* __restrict__ users,
                             const int* __restrict__ items, const float* __restrict__ S,
                             const float* __restrict__ zp, float* __restrict__ out) {
    int gid = blockIdx.x * blockDim.x + threadIdx.x;
    int b = gid >> 6, lane = gid & 63;
    if (b >= BATCH) return;
    float z = fmaxf(*zp, 1e-12f);
    float na = S[lane] / z;
    int u = users[b], it = items[b] + NUM_USERS;
    float v = bf2f(x[u * DIM + lane]) * (bf2f(x[it * DIM + lane]) + na);
    v = wave_sum64(v);
    if (lane == 0) out[b] = 1.0f / (1.0f + __expf(-v));
}

// ---- launch -------------------------------------------------------------

extern "C" void kernel_launch(void* const* d_in, const int* in_sizes, int n_in,
                              void* d_out, int out_size, void* d_ws, size_t ws_size,
                              hipStream_t stream) {
    const float* embed = (const float*)d_in[0];
    const int*   edge  = (const int*)d_in[1];
    const int*   row   = edge;
    const int*   col   = edge + NEDGE;
    const int*   users = (const int*)d_in[2];
    const int*   items = (const int*)d_in[3];
    float*       out   = (float*)d_out;
    char*        ws    = (char*)d_ws;

    size_t off = 0;
    auto A = [&](size_t bytes) { size_t o = off; off += (bytes + 255) & ~(size_t)255; return o; };
    // big region: midC (8 MB) + midR (4 MB) during build; xa (19.2 MB) after
    size_t o_big   = A((size_t)NNODES * DIM * 2);      // 19.2 MB
    size_t o_xb    = A((size_t)NNODES * DIM * 2);      // 19.2 MB
    size_t o_src   = A((size_t)NEDGE * 4);             // 8 MB, alive thru prop
    size_t o_rkR   = A((size_t)SLICES * EPS);          // 2 MB
    size_t o_rkC   = A((size_t)SLICES * EPS);          // 2 MB
    size_t o_cntR  = A((size_t)SLICES * NBUK * 2);     // 300 KB
    size_t o_cntC  = A((size_t)SLICES * NBUK * 2);
    size_t o_offR  = A((size_t)SLICES * NBUK * 2);
    size_t o_offC  = A((size_t)SLICES * NBUK * 2);
    size_t o_tot   = A((size_t)2 * NBUK * 4);
    size_t o_baseR = A((size_t)(NBUK + 1) * 4);
    size_t o_baseC = A((size_t)(NBUK + 1) * 4);
    size_t o_selc  = A((size_t)SEL_CAP * 4);
    size_t o_selw  = A((size_t)SEL_CAP * 4);
    size_t o_sell  = A((size_t)SEL_CAP * 4);
    size_t o_part  = A((size_t)256 * 64 * 4);          // ctx partials
    size_t o_zero  = off;                              // ---- zeroed block ----
    size_t o_ucnt  = A((size_t)NNODES * 4);
    size_t o_misc  = A(1024);                          // n_sel@0, mx@4, z@8, S@256
    size_t zero_bytes = off - o_zero;                  // ---- end zero -------
    size_t o_dinv  = A((size_t)NNODES * 4);
    size_t o_dinv2 = A((size_t)NNODES * 4);
    size_t o_rptr  = A((size_t)(NNODES + 1) * 4);
    size_t o_bmax  = A((size_t)LOGIT_BLOCKS * 4);
    size_t o_ctx   = A(256);

    unsigned int*   midC = (unsigned int*)(ws + o_big);                // 8 MB
    unsigned short* midR = (unsigned short*)(ws + o_big + (size_t)NEDGE * 4);  // 4 MB
    unsigned short* xa   = (unsigned short*)(ws + o_big);              // overlay after build
    unsigned short* xb   = (unsigned short*)(ws + o_xb);
    int*   srcS  = (int*)(ws + o_src);
    unsigned char* rkR = (unsigned char*)(ws + o_rkR);
    unsigned char* rkC = (unsigned char*)(ws + o_rkC);
    unsigned short* cntR = (unsigned short*)(ws + o_cntR);
    unsigned short* cntC = (unsigned short*)(ws + o_cntC);
    unsigned short* offR = (unsigned short*)(ws + o_offR);
    unsigned short* offC = (unsigned short*)(ws + o_offC);
    int*   totRC = (int*)(ws + o_tot);
    int*   baseR = (int*)(ws + o_baseR);
    int*   baseC = (int*)(ws + o_baseC);
    int*   selc  = (int*)(ws + o_selc);
    float* selw  = (float*)(ws + o_selw);
    float* sell  = (float*)(ws + o_sell);
    float* part  = (float*)(ws + o_part);
    int*   ucnt  = (int*)(ws + o_ucnt);
    int*   nsel  = (int*)(ws + o_misc);
    float* mx    = (float*)(ws + o_misc + 4);
    float* zp    = (float*)(ws + o_misc + 8);
    float* S     = (float*)(ws + o_misc + 256);
    float* dinv  = (float*)(ws + o_dinv);
    float* dinv2 = (float*)(ws + o_dinv2);
    int*   rptr  = (int*)(ws + o_rptr);
    float* bmax  = (float*)(ws + o_bmax);
    float* ctx   = (float*)(ws + o_ctx);

    hipMemsetAsync(ws + o_zero, 0, zero_bytes, stream);

    ucnt_kernel<<<(BATCH + 255) / 256, 256, 0, stream>>>(users, ucnt);

    // atomic-free CSR build
    bhist_kernel<<<SLICES, 512, 0, stream>>>(row, col, cntR, cntC, rkR, rkC);
    bprefix1_kernel<<<2 * NBUK, 512, 0, stream>>>(cntR, cntC, offR, offC, totRC);
    bprefix2_kernel<<<2, 512, 0, stream>>>(totRC, baseR, baseC);
    // standalone low-atomic selection (isolated from placement)
    select_kernel<<<SELB, 256, 0, stream>>>(row, col, ucnt, nsel, selc, selw);
    place_kernel<<<SLICES, 512, 0, stream>>>(row, col, rkR, rkC, cntR, cntC,
                                             offR, offC, baseR, baseC, midR, midC);
    bfinal_col_kernel<<<NBUK, 1024, 0, stream>>>(midC, baseC, rptr, srcS);
    bfinal_row_kernel<<<NBUK, 1024, 0, stream>>>(midR, baseR, dinv, dinv2);

    // y0 = bf16(dinv*embed); layers: y->y (dinv2), y->y (dinv2), y->x (dinv)
    cvt_kernel<<<(NNODES * 16 + 255) / 256, 256, 0, stream>>>((const float4*)embed, (uint2*)xa, dinv);
    int prop_blocks = (NNODES * 16 + 255) / 256;
    prop_kernel<<<prop_blocks, 256, 0, stream>>>((const uint2*)xa, (uint2*)xb, rptr, srcS, dinv2);
    prop_kernel<<<prop_blocks, 256, 0, stream>>>((const uint2*)xb, (uint2*)xa, rptr, srcS, dinv2);
    prop_kernel<<<prop_blocks, 256, 0, stream>>>((const uint2*)xa, (uint2*)xb, rptr, srcS, dinv);
    // final x lives in xb

    // batch softmax aggregation over selected edges
    ctx_part_kernel<<<256, 256, 0, stream>>>(xb, users, part);
    ctx_reduce_kernel<<<1, 256, 0, stream>>>(part, ctx);
    logit_kernel<<<LOGIT_BLOCKS, 256, 0, stream>>>(xb, ctx, selc, nsel, sell, bmax);
    max_kernel<<<1, 256, 0, stream>>>(bmax, mx);
    accum_kernel<<<LOGIT_BLOCKS, 256, 0, stream>>>(xb, selc, selw, sell, nsel, mx, S, zp);

    // final scores
    score_kernel<<<(BATCH * 64 + 255) / 256, 256, 0, stream>>>(xb, users, items, S, zp, out);
}

// Round 14
// 331.161 us; speedup vs baseline: 1.7339x; 1.0303x over previous
//
#include <hip/hip_runtime.h>
#include <float.h>
#include <math.h>

#define NUM_USERS 100000
#define NUM_ITEMS 50000
#define NNODES    150000
#define DIM       64
#define NEDGE     2000000
#define BATCH     1024
#define SEL_CAP   (1 << 18)
#define LOGIT_BLOCKS 512

#define SLICES   512                    // edge slices (= threads in bprefix1 scan)
#define EPS      3908                   // ceil(NEDGE/SLICES) rounded to x4
#define NBUK     293                    // buckets of 512 nodes (293*512=150016)
#define SELB     977                    // ceil(NEDGE/2048) selection blocks

__device__ __forceinline__ float wave_sum64(float v) {
    #pragma unroll
    for (int off = 32; off > 0; off >>= 1) v += __shfl_xor(v, off, 64);
    return v;
}

__device__ __forceinline__ float bf2f(unsigned short s) {
    return __uint_as_float(((unsigned int)s) << 16);
}
__device__ __forceinline__ unsigned short f2bf(float f) {   // RNE
    unsigned int u = __float_as_uint(f);
    return (unsigned short)((u + 0x7fffu + ((u >> 16) & 1u)) >> 16);
}

// ---- stage 1: per-slice 293-bucket histograms + u8 rank capture ---------

__global__ __launch_bounds__(512) void bhist_kernel(
        const int* __restrict__ row, const int* __restrict__ col,
        unsigned short* __restrict__ cntR, unsigned short* __restrict__ cntC,
        unsigned char* __restrict__ rkR, unsigned char* __restrict__ rkC) {
    __shared__ unsigned int hr[NBUK], hc[NBUK];
    int blk = blockIdx.x, t = threadIdx.x;
    for (int i = t; i < NBUK; i += 512) { hr[i] = 0; hc[i] = 0; }
    __syncthreads();
    int e0 = blk * EPS;
    int e1 = e0 + EPS; if (e1 > NEDGE) e1 = NEDGE;
    for (int base = e0 + t * 4; base < e1; base += 2048) {
        if (base + 4 <= e1) {
            int4 r4 = *(const int4*)(row + base);
            int4 c4 = *(const int4*)(col + base);
            uchar4 a, b;
            a.x = (unsigned char)atomicAdd(&hr[r4.x >> 9], 1u);
            a.y = (unsigned char)atomicAdd(&hr[r4.y >> 9], 1u);
            a.z = (unsigned char)atomicAdd(&hr[r4.z >> 9], 1u);
            a.w = (unsigned char)atomicAdd(&hr[r4.w >> 9], 1u);
            b.x = (unsigned char)atomicAdd(&hc[c4.x >> 9], 1u);
            b.y = (unsigned char)atomicAdd(&hc[c4.y >> 9], 1u);
            b.z = (unsigned char)atomicAdd(&hc[c4.z >> 9], 1u);
            b.w = (unsigned char)atomicAdd(&hc[c4.w >> 9], 1u);
            *(uchar4*)(rkR + base) = a;
            *(uchar4*)(rkC + base) = b;
        } else {
            for (int e = base; e < e1; ++e) {
                rkR[e] = (unsigned char)atomicAdd(&hr[row[e] >> 9], 1u);
                rkC[e] = (unsigned char)atomicAdd(&hc[col[e] >> 9], 1u);
            }
        }
    }
    __syncthreads();
    for (int i = t; i < NBUK; i += 512) {
        cntR[(size_t)blk * NBUK + i] = (unsigned short)hr[i];
        cntC[(size_t)blk * NBUK + i] = (unsigned short)hc[i];
    }
}

// ---- stage 2: parallel per-bucket prefix over slices ---------------------

__global__ __launch_bounds__(512) void bprefix1_kernel(
        const unsigned short* __restrict__ cntR, const unsigned short* __restrict__ cntC,
        unsigned short* __restrict__ offR, unsigned short* __restrict__ offC,
        int* __restrict__ totRC) {
    int side = blockIdx.x / NBUK;
    int b = blockIdx.x - side * NBUK;
    const unsigned short* cnt = side ? cntC : cntR;
    unsigned short* off = side ? offC : offR;
    __shared__ int sm[512];
    int t = threadIdx.x;
    int v = (int)cnt[(size_t)t * NBUK + b];
    sm[t] = v;
    __syncthreads();
    for (int o = 1; o < 512; o <<= 1) {
        int x = (t >= o) ? sm[t - o] : 0;
        __syncthreads();
        sm[t] += x;
        __syncthreads();
    }
    off[(size_t)t * NBUK + b] = (unsigned short)(sm[t] - v);
    if (t == 511) totRC[side * NBUK + b] = sm[511];
}

__global__ __launch_bounds__(512) void bprefix2_kernel(
        const int* __restrict__ totRC, int* __restrict__ baseR, int* __restrict__ baseC) {
    const int* tot = totRC + blockIdx.x * NBUK;
    int* base = blockIdx.x ? baseC : baseR;
    __shared__ int sm[512];
    int t = threadIdx.x;
    int v = (t < NBUK) ? tot[t] : 0;
    sm[t] = v;
    __syncthreads();
    for (int o = 1; o < 512; o <<= 1) {
        int x = (t >= o) ? sm[t - o] : 0;
        __syncthreads();
        sm[t] += x;
        __syncthreads();
    }
    if (t < NBUK) base[t] = sm[t] - v;
    if (t == NBUK - 1) base[NBUK] = sm[t];     // == NEDGE
}

// ---- batch-edge selection (standalone, low-atomic) -----------------------

__global__ __launch_bounds__(256) void select_kernel(
        const int* __restrict__ row, const int* __restrict__ col,
        const int* __restrict__ ucnt,
        int* __restrict__ n_sel, int* __restrict__ sel_col, float* __restrict__ sel_w) {
    __shared__ int lcnt, lbase;
    __shared__ int2 buf[512];
    if (threadIdx.x == 0) lcnt = 0;
    __syncthreads();
    int e0 = blockIdx.x * 2048;
    int e1 = e0 + 2048; if (e1 > NEDGE) e1 = NEDGE;
    for (int base = e0 + (int)threadIdx.x * 4; base < e1; base += 1024) {
        if (base + 4 <= e1) {
            int4 r4 = *(const int4*)(row + base);
            int4 c4 = *(const int4*)(col + base);
            int u0 = ucnt[r4.x], u1 = ucnt[r4.y], u2 = ucnt[r4.z], u3 = ucnt[r4.w];
            if (u0 > 0) { int i = atomicAdd(&lcnt, 1); if (i < 512) buf[i] = make_int2(c4.x, u0); }
            if (u1 > 0) { int i = atomicAdd(&lcnt, 1); if (i < 512) buf[i] = make_int2(c4.y, u1); }
            if (u2 > 0) { int i = atomicAdd(&lcnt, 1); if (i < 512) buf[i] = make_int2(c4.z, u2); }
            if (u3 > 0) { int i = atomicAdd(&lcnt, 1); if (i < 512) buf[i] = make_int2(c4.w, u3); }
        } else {
            for (int e = base; e < e1; ++e) {
                int u = ucnt[row[e]];
                if (u > 0) { int i = atomicAdd(&lcnt, 1); if (i < 512) buf[i] = make_int2(col[e], u); }
            }
        }
    }
    __syncthreads();
    if (threadIdx.x == 0) {
        int c = lcnt; c = c < 512 ? c : 512;
        lbase = atomicAdd(n_sel, c);
    }
    __syncthreads();
    int c = lcnt; c = c < 512 ? c : 512;
    int b = lbase;
    for (int i = threadIdx.x; i < c; i += 256) {
        int o = b + i;
        if (o < SEL_CAP) { sel_col[o] = buf[i].x; sel_w[o] = (float)buf[i].y; }
    }
}

// ---- stage 3: placement -- pure LDS-staged slice sort, burst write-out ---

__global__ __launch_bounds__(512) void place_kernel(
        const int* __restrict__ row, const int* __restrict__ col,
        const unsigned char* __restrict__ rkR, const unsigned char* __restrict__ rkC,
        const unsigned short* __restrict__ cntR, const unsigned short* __restrict__ cntC,
        const unsigned short* __restrict__ offR, const unsigned short* __restrict__ offC,
        const int* __restrict__ baseR, const int* __restrict__ baseC,
        unsigned short* __restrict__ midR, unsigned int* __restrict__ midC) {
    __shared__ int lofC[NBUK], lofR[NBUK], posC[NBUK], posR[NBUK];
    __shared__ int cCl[NBUK], cRl[NBUK];
    __shared__ int scan_tmp[512];
    __shared__ unsigned int   stC[EPS];
    __shared__ unsigned short stR[EPS];
    int blk = blockIdx.x, t = threadIdx.x;
    if (t < NBUK) {
        cCl[t] = (int)cntC[(size_t)blk * NBUK + t];
        cRl[t] = (int)cntR[(size_t)blk * NBUK + t];
        posC[t] = baseC[t] + (int)offC[(size_t)blk * NBUK + t];
        posR[t] = baseR[t] + (int)offR[(size_t)blk * NBUK + t];
    }
    __syncthreads();
    scan_tmp[t] = (t < NBUK) ? cCl[t] : 0;
    __syncthreads();
    for (int o = 1; o < 512; o <<= 1) {
        int v = (t >= o) ? scan_tmp[t - o] : 0;
        __syncthreads();
        scan_tmp[t] += v;
        __syncthreads();
    }
    if (t < NBUK) lofC[t] = scan_tmp[t] - cCl[t];
    __syncthreads();
    scan_tmp[t] = (t < NBUK) ? cRl[t] : 0;
    __syncthreads();
    for (int o = 1; o < 512; o <<= 1) {
        int v = (t >= o) ? scan_tmp[t - o] : 0;
        __syncthreads();
        scan_tmp[t] += v;
        __syncthreads();
    }
    if (t < NBUK) lofR[t] = scan_tmp[t] - cRl[t];
    __syncthreads();
    int e0 = blk * EPS;
    int e1 = e0 + EPS; if (e1 > NEDGE) e1 = NEDGE;
    for (int base = e0 + t * 4; base < e1; base += 2048) {
        if (base + 4 <= e1) {
            int4 r4 = *(const int4*)(row + base);
            int4 c4 = *(const int4*)(col + base);
            uchar4 kr = *(const uchar4*)(rkR + base);
            uchar4 kc = *(const uchar4*)(rkC + base);
            stC[lofC[c4.x >> 9] + (int)kc.x] = ((unsigned int)(c4.x & 511) << 18) | (unsigned int)r4.x;
            stC[lofC[c4.y >> 9] + (int)kc.y] = ((unsigned int)(c4.y & 511) << 18) | (unsigned int)r4.y;
            stC[lofC[c4.z >> 9] + (int)kc.z] = ((unsigned int)(c4.z & 511) << 18) | (unsigned int)r4.z;
            stC[lofC[c4.w >> 9] + (int)kc.w] = ((unsigned int)(c4.w & 511) << 18) | (unsigned int)r4.w;
            stR[lofR[r4.x >> 9] + (int)kr.x] = (unsigned short)(r4.x & 511);
            stR[lofR[r4.y >> 9] + (int)kr.y] = (unsigned short)(r4.y & 511);
            stR[lofR[r4.z >> 9] + (int)kr.z] = (unsigned short)(r4.z & 511);
            stR[lofR[r4.w >> 9] + (int)kr.w] = (unsigned short)(r4.w & 511);
        } else {
            for (int e = base; e < e1; ++e) {
                int r = row[e], c = col[e];
                stC[lofC[c >> 9] + (int)rkC[e]] = ((unsigned int)(c & 511) << 18) | (unsigned int)r;
                stR[lofR[r >> 9] + (int)rkR[e]] = (unsigned short)(r & 511);
            }
        }
    }
    __syncthreads();
    int wave = t >> 6, lane = t & 63;
    for (int b = wave; b < NBUK; b += 8) {
        int n = cCl[b], lo = lofC[b], dst = posC[b];
        for (int i = lane; i < n; i += 64) midC[dst + i] = stC[lo + i];
        n = cRl[b]; lo = lofR[b]; dst = posR[b];
        for (int i = lane; i < n; i += 64) midR[dst + i] = stR[lo + i];
    }
}

// ---- stage 4a: per col-bucket: count -> scan -> rptr + permute to CSR ----

__global__ __launch_bounds__(1024) void bfinal_col_kernel(
        const unsigned int* __restrict__ midC, const int* __restrict__ baseC,
        int* __restrict__ rptr, int* __restrict__ src_sorted) {
    __shared__ int cnt[512], sm[512], cur[512];
    int b = blockIdx.x;
    int s0 = baseC[b], s1 = baseC[b + 1];
    int t = threadIdx.x;
    if (t < 512) cnt[t] = 0;
    __syncthreads();
    for (int i = s0 + t; i < s1; i += 1024) atomicAdd(&cnt[midC[i] >> 18], 1);
    __syncthreads();
    if (t < 512) sm[t] = cnt[t];
    __syncthreads();
    for (int off = 1; off < 512; off <<= 1) {
        int v = 0;
        if (t < 512 && t >= off) v = sm[t - off];
        __syncthreads();
        if (t < 512) sm[t] += v;
        __syncthreads();
    }
    if (t < 512) {
        int excl = s0 + sm[t] - cnt[t];
        int n = b * 512 + t;
        if (n < NNODES) rptr[n] = excl;
        cur[t] = excl;
    }
    if (b == NBUK - 1 && t == 0) rptr[NNODES] = s1;   // == NEDGE
    __syncthreads();
    for (int i = s0 + t; i < s1; i += 1024) {
        unsigned int v = midC[i];
        int dst = atomicAdd(&cur[v >> 18], 1);
        src_sorted[dst] = (int)(v & 0x3FFFFu);
    }
}

// ---- stage 4b: per row-bucket: count -> dinv / dinv2 ---------------------

__global__ __launch_bounds__(1024) void bfinal_row_kernel(
        const unsigned short* __restrict__ midR, const int* __restrict__ baseR,
        float* __restrict__ dinv, float* __restrict__ dinv2) {
    __shared__ int cnt[512];
    int b = blockIdx.x;
    int s0 = baseR[b], s1 = baseR[b + 1];
    int t = threadIdx.x;
    if (t < 512) cnt[t] = 0;
    __syncthreads();
    for (int i = s0 + t; i < s1; i += 1024) atomicAdd(&cnt[midR[i]], 1);
    __syncthreads();
    if (t < 512) {
        int n = b * 512 + t;
        if (n < NNODES) {
            float d = fmaxf((float)cnt[t], 1.0f);
            dinv[n] = rsqrtf(d);
            dinv2[n] = 1.0f / d;
        }
    }
}

// ---- f32 embed -> bf16 y0 = dinv * x0 -----------------------------------

__global__ void cvt_kernel(const float4* __restrict__ src, uint2* __restrict__ dst,
                           const float* __restrict__ dinv) {
    int t = blockIdx.x * blockDim.x + threadIdx.x;   // one uint2 = 4 bf16
    if (t >= NNODES * 16) return;
    float d = dinv[t >> 4];
    float4 v = src[t];
    unsigned int w0 = (unsigned int)f2bf(v.x * d) | ((unsigned int)f2bf(v.y * d) << 16);
    unsigned int w1 = (unsigned int)f2bf(v.z * d) | ((unsigned int)f2bf(v.w * d) << 16);
    dst[t] = make_uint2(w0, w1);
}

// ---- propagation: 8 lanes/node, uint4 (8 bf16) per lane ------------------
// 8 independent node streams per wave, 16B loads: 2x bytes in flight vs
// the uint2 version (R12: 43.7 us/layer, 3.0 TB/s, latency-limited).

__global__ void prop_kernel(const uint4* __restrict__ x_in, uint4* __restrict__ x_out,
                            const int* __restrict__ ptr, const int* __restrict__ src,
                            const float* __restrict__ scale) {
    int gid  = blockIdx.x * blockDim.x + threadIdx.x;
    int node = gid >> 3;       // 8 lanes per node
    int sl   = gid & 7;        // lane's 8-dim slot within the row
    if (node >= NNODES) return;
    int s = ptr[node], e = ptr[node + 1];
    float a0 = 0.f, a1 = 0.f, a2 = 0.f, a3 = 0.f;
    float a4 = 0.f, a5 = 0.f, a6 = 0.f, a7 = 0.f;
    int i = s;
    for (; i + 4 <= e; i += 4) {
        int s0 = src[i], s1 = src[i + 1], s2 = src[i + 2], s3 = src[i + 3];
        uint4 w0 = x_in[s0 * 8 + sl];
        uint4 w1 = x_in[s1 * 8 + sl];
        uint4 w2 = x_in[s2 * 8 + sl];
        uint4 w3 = x_in[s3 * 8 + sl];
        a0 += __uint_as_float(w0.x << 16); a1 += __uint_as_float(w0.x & 0xffff0000u);
        a2 += __uint_as_float(w0.y << 16); a3 += __uint_as_float(w0.y & 0xffff0000u);
        a4 += __uint_as_float(w0.z << 16); a5 += __uint_as_float(w0.z & 0xffff0000u);
        a6 += __uint_as_float(w0.w << 16); a7 += __uint_as_float(w0.w & 0xffff0000u);
        a0 += __uint_as_float(w1.x << 16); a1 += __uint_as_float(w1.x & 0xffff0000u);
        a2 += __uint_as_float(w1.y << 16); a3 += __uint_as_float(w1.y & 0xffff0000u);
        a4 += __uint_as_float(w1.z << 16); a5 += __uint_as_float(w1.z & 0xffff0000u);
        a6 += __uint_as_float(w1.w << 16); a7 += __uint_as_float(w1.w & 0xffff0000u);
        a0 += __uint_as_float(w2.x << 16); a1 += __uint_as_float(w2.x & 0xffff0000u);
        a2 += __uint_as_float(w2.y << 16); a3 += __uint_as_float(w2.y & 0xffff0000u);
        a4 += __uint_as_float(w2.z << 16); a5 += __uint_as_float(w2.z & 0xffff0000u);
        a6 += __uint_as_float(w2.w << 16); a7 += __uint_as_float(w2.w & 0xffff0000u);
        a0 += __uint_as_float(w3.x << 16); a1 += __uint_as_float(w3.x & 0xffff0000u);
        a2 += __uint_as_float(w3.y << 16); a3 += __uint_as_float(w3.y & 0xffff0000u);
        a4 += __uint_as_float(w3.z << 16); a5 += __uint_as_float(w3.z & 0xffff0000u);
        a6 += __uint_as_float(w3.w << 16); a7 += __uint_as_float(w3.w & 0xffff0000u);
    }
    for (; i < e; ++i) {
        uint4 w0 = x_in[src[i] * 8 + sl];
        a0 += __uint_as_float(w0.x << 16); a1 += __uint_as_float(w0.x & 0xffff0000u);
        a2 += __uint_as_float(w0.y << 16); a3 += __uint_as_float(w0.y & 0xffff0000u);
        a4 += __uint_as_float(w0.z << 16); a5 += __uint_as_float(w0.z & 0xffff0000u);
        a6 += __uint_as_float(w0.w << 16); a7 += __uint_as_float(w0.w & 0xffff0000u);
    }
    float sc = scale[node];
    uint4 o;
    o.x = (unsigned int)f2bf(a0 * sc) | ((unsigned int)f2bf(a1 * sc) << 16);
    o.y = (unsigned int)f2bf(a2 * sc) | ((unsigned int)f2bf(a3 * sc) << 16);
    o.z = (unsigned int)f2bf(a4 * sc) | ((unsigned int)f2bf(a5 * sc) << 16);
    o.w = (unsigned int)f2bf(a6 * sc) | ((unsigned int)f2bf(a7 * sc) << 16);
    x_out[node * 8 + sl] = o;
}

// ---- batch / softmax part (x is bf16) -----------------------------------

__global__ void ucnt_kernel(const int* __restrict__ users, int* __restrict__ ucnt) {
    int b = blockIdx.x * blockDim.x + threadIdx.x;
    if (b < BATCH) atomicAdd(&ucnt[users[b]], 1);
}

// ctx phase 1: 256 blocks x 4 waves; wave w of block b loads user row 4b+w.
__global__ __launch_bounds__(256) void ctx_part_kernel(
        const unsigned short* __restrict__ x, const int* __restrict__ users,
        float* __restrict__ partial) {
    __shared__ float sm[256];
    int lane = threadIdx.x & 63, wl = threadIdx.x >> 6;
    int b = blockIdx.x * 4 + wl;
    float v = (b < BATCH) ? bf2f(x[users[b] * DIM + lane]) : 0.0f;
    sm[threadIdx.x] = v;
    __syncthreads();
    if (wl == 0)
        partial[blockIdx.x * 64 + lane] =
            sm[lane] + sm[64 + lane] + sm[128 + lane] + sm[192 + lane];
}

// ctx phase 2: reduce 256 partials -> ctx (mean over BATCH)
__global__ __launch_bounds__(256) void ctx_reduce_kernel(
        const float* __restrict__ partial, float* __restrict__ ctx) {
    __shared__ float sm[256];
    int lane = threadIdx.x & 63, wl = threadIdx.x >> 6;
    float acc = 0.0f;
    for (int i = wl; i < 256; i += 4) acc += partial[i * 64 + lane];
    sm[threadIdx.x] = acc;
    __syncthreads();
    if (wl == 0)
        ctx[lane] = (sm[lane] + sm[64 + lane] + sm[128 + lane] + sm[192 + lane])
                    * (1.0f / BATCH);
}

__global__ void logit_kernel(const unsigned short* __restrict__ x, const float* __restrict__ ctx,
                             const int* __restrict__ sel_col, const int* __restrict__ n_sel_p,
                             float* __restrict__ sel_logit, float* __restrict__ blk_max) {
    __shared__ float sm[4];
    int lane = threadIdx.x & 63, wl = threadIdx.x >> 6;
    int n = *n_sel_p; if (n > SEL_CAP) n = SEL_CAP;
    float c = ctx[lane];
    float bmax = -FLT_MAX;
    int stride = gridDim.x * 4;
    for (int idx = blockIdx.x * 4 + wl; idx < n; idx += stride) {
        int node = sel_col[idx];
        float v = bf2f(x[node * DIM + lane]) * c;
        v = wave_sum64(v);
        if (lane == 0) sel_logit[idx] = v;
        bmax = fmaxf(bmax, v);
    }
    if (lane == 0) sm[wl] = bmax;
    __syncthreads();
    if (threadIdx.x == 0)
        blk_max[blockIdx.x] = fmaxf(fmaxf(sm[0], sm[1]), fmaxf(sm[2], sm[3]));
}

__global__ void max_kernel(const float* __restrict__ blk_max, float* __restrict__ mx) {
    __shared__ float sm[256];
    int t = threadIdx.x;
    float m = fmaxf(blk_max[t], blk_max[t + 256]);
    sm[t] = m; __syncthreads();
    for (int off = 128; off > 0; off >>= 1) {
        if (t < off) sm[t] = fmaxf(sm[t], sm[t + off]);
        __syncthreads();
    }
    if (t == 0) *mx = sm[0];
}

__global__ void accum_kernel(const unsigned short* __restrict__ x, const int* __restrict__ sel_col,
                             const float* __restrict__ sel_w, const float* __restrict__ sel_logit,
                             const int* __restrict__ n_sel_p, const float* __restrict__ mx_p,
                             float* __restrict__ S, float* __restrict__ zp) {
    __shared__ float smS[4 * 64];
    __shared__ float smZ[4];
    int lane = threadIdx.x & 63, wl = threadIdx.x >> 6;
    int n = *n_sel_p; if (n > SEL_CAP) n = SEL_CAP;
    float mx = *mx_p;
    float accS = 0.0f, accZ = 0.0f;
    int stride = gridDim.x * 4;
    for (int idx = blockIdx.x * 4 + wl; idx < n; idx += stride) {
        int node = sel_col[idx];
        float w = sel_w[idx] * __expf(sel_logit[idx] - mx);
        accS = fmaf(w, bf2f(x[node * DIM + lane]), accS);
        accZ += w;
    }
    smS[wl * 64 + lane] = accS;
    if (lane == 0) smZ[wl] = accZ;
    __syncthreads();
    if (wl == 0) {
        float s = smS[lane] + smS[64 + lane] + smS[128 + lane] + smS[192 + lane];
        atomicAdd(&S[lane], s);
    }
    if (threadIdx.x == 0) atomicAdd(zp, smZ[0] + smZ[1] + smZ[2] + smZ[3]);
}

__global__ void score_kernel(const unsigned short* __restrict__ x, const int* __restrict__ users,
                             const int* __restrict__ items, const float* __restrict__ S,
                             const float* __restrict__ zp, float* __restrict__ out) {
    int gid = blockIdx.x * blockDim.x + threadIdx.x;
    int b = gid >> 6, lane = gid & 63;
    if (b >= BATCH) return;
    float z = fmaxf(*zp, 1e-12f);
    float na = S[lane] / z;
    int u = users[b], it = items[b] + NUM_USERS;
    float v = bf2f(x[u * DIM + lane]) * (bf2f(x[it * DIM + lane]) + na);
    v = wave_sum64(v);
    if (lane == 0) out[b] = 1.0f / (1.0f + __expf(-v));
}

// ---- launch -------------------------------------------------------------

extern "C" void kernel_launch(void* const* d_in, const int* in_sizes, int n_in,
                              void* d_out, int out_size, void* d_ws, size_t ws_size,
                              hipStream_t stream) {
    const float* embed = (const float*)d_in[0];
    const int*   edge  = (const int*)d_in[1];
    const int*   row   = edge;
    const int*   col   = edge + NEDGE;
    const int*   users = (const int*)d_in[2];
    const int*   items = (const int*)d_in[3];
    float*       out   = (float*)d_out;
    char*        ws    = (char*)d_ws;

    size_t off = 0;
    auto A = [&](size_t bytes) { size_t o = off; off += (bytes + 255) & ~(size_t)255; return o; };
    // big region: midC (8 MB) + midR (4 MB) during build; xa (19.2 MB) after
    size_t o_big   = A((size_t)NNODES * DIM * 2);      // 19.2 MB
    size_t o_xb    = A((size_t)NNODES * DIM * 2);      // 19.2 MB
    size_t o_src   = A((size_t)NEDGE * 4);             // 8 MB, alive thru prop
    size_t o_rkR   = A((size_t)SLICES * EPS);          // 2 MB
    size_t o_rkC   = A((size_t)SLICES * EPS);          // 2 MB
    size_t o_cntR  = A((size_t)SLICES * NBUK * 2);     // 300 KB
    size_t o_cntC  = A((size_t)SLICES * NBUK * 2);
    size_t o_offR  = A((size_t)SLICES * NBUK * 2);
    size_t o_offC  = A((size_t)SLICES * NBUK * 2);
    size_t o_tot   = A((size_t)2 * NBUK * 4);
    size_t o_baseR = A((size_t)(NBUK + 1) * 4);
    size_t o_baseC = A((size_t)(NBUK + 1) * 4);
    size_t o_selc  = A((size_t)SEL_CAP * 4);
    size_t o_selw  = A((size_t)SEL_CAP * 4);
    size_t o_sell  = A((size_t)SEL_CAP * 4);
    size_t o_part  = A((size_t)256 * 64 * 4);          // ctx partials
    size_t o_zero  = off;                              // ---- zeroed block ----
    size_t o_ucnt  = A((size_t)NNODES * 4);
    size_t o_misc  = A(1024);                          // n_sel@0, mx@4, z@8, S@256
    size_t zero_bytes = off - o_zero;                  // ---- end zero -------
    size_t o_dinv  = A((size_t)NNODES * 4);
    size_t o_dinv2 = A((size_t)NNODES * 4);
    size_t o_rptr  = A((size_t)(NNODES + 1) * 4);
    size_t o_bmax  = A((size_t)LOGIT_BLOCKS * 4);
    size_t o_ctx   = A(256);

    unsigned int*   midC = (unsigned int*)(ws + o_big);                // 8 MB
    unsigned short* midR = (unsigned short*)(ws + o_big + (size_t)NEDGE * 4);  // 4 MB
    unsigned short* xa   = (unsigned short*)(ws + o_big);              // overlay after build
    unsigned short* xb   = (unsigned short*)(ws + o_xb);
    int*   srcS  = (int*)(ws + o_src);
    unsigned char* rkR = (unsigned char*)(ws + o_rkR);
    unsigned char* rkC = (unsigned char*)(ws + o_rkC);
    unsigned short* cntR = (unsigned short*)(ws + o_cntR);
    unsigned short* cntC = (unsigned short*)(ws + o_cntC);
    unsigned short* offR = (unsigned short*)(ws + o_offR);
    unsigned short* offC = (unsigned short*)(ws + o_offC);
    int*   totRC = (int*)(ws + o_tot);
    int*   baseR = (int*)(ws + o_baseR);
    int*   baseC = (int*)(ws + o_baseC);
    int*   selc  = (int*)(ws + o_selc);
    float* selw  = (float*)(ws + o_selw);
    float* sell  = (float*)(ws + o_sell);
    float* part  = (float*)(ws + o_part);
    int*   ucnt  = (int*)(ws + o_ucnt);
    int*   nsel  = (int*)(ws + o_misc);
    float* mx    = (float*)(ws + o_misc + 4);
    float* zp    = (float*)(ws + o_misc + 8);
    float* S     = (float*)(ws + o_misc + 256);
    float* dinv  = (float*)(ws + o_dinv);
    float* dinv2 = (float*)(ws + o_dinv2);
    int*   rptr  = (int*)(ws + o_rptr);
    float* bmax  = (float*)(ws + o_bmax);
    float* ctx   = (float*)(ws + o_ctx);

    hipMemsetAsync(ws + o_zero, 0, zero_bytes, stream);

    ucnt_kernel<<<(BATCH + 255) / 256, 256, 0, stream>>>(users, ucnt);

    // atomic-free CSR build
    bhist_kernel<<<SLICES, 512, 0, stream>>>(row, col, cntR, cntC, rkR, rkC);
    bprefix1_kernel<<<2 * NBUK, 512, 0, stream>>>(cntR, cntC, offR, offC, totRC);
    bprefix2_kernel<<<2, 512, 0, stream>>>(totRC, baseR, baseC);
    // standalone low-atomic selection (isolated from placement)
    select_kernel<<<SELB, 256, 0, stream>>>(row, col, ucnt, nsel, selc, selw);
    place_kernel<<<SLICES, 512, 0, stream>>>(row, col, rkR, rkC, cntR, cntC,
                                             offR, offC, baseR, baseC, midR, midC);
    bfinal_col_kernel<<<NBUK, 1024, 0, stream>>>(midC, baseC, rptr, srcS);
    bfinal_row_kernel<<<NBUK, 1024, 0, stream>>>(midR, baseR, dinv, dinv2);

    // y0 = bf16(dinv*embed); layers: y->y (dinv2), y->y (dinv2), y->x (dinv)
    cvt_kernel<<<(NNODES * 16 + 255) / 256, 256, 0, stream>>>((const float4*)embed, (uint2*)xa, dinv);
    int prop_blocks = (NNODES * 8 + 255) / 256;
    prop_kernel<<<prop_blocks, 256, 0, stream>>>((const uint4*)xa, (uint4*)xb, rptr, srcS, dinv2);
    prop_kernel<<<prop_blocks, 256, 0, stream>>>((const uint4*)xb, (uint4*)xa, rptr, srcS, dinv2);
    prop_kernel<<<prop_blocks, 256, 0, stream>>>((const uint4*)xa, (uint4*)xb, rptr, srcS, dinv);
    // final x lives in xb

    // batch softmax aggregation over selected edges
    ctx_part_kernel<<<256, 256, 0, stream>>>(xb, users, part);
    ctx_reduce_kernel<<<1, 256, 0, stream>>>(part, ctx);
    logit_kernel<<<LOGIT_BLOCKS, 256, 0, stream>>>(xb, ctx, selc, nsel, sell, bmax);
    max_kernel<<<1, 256, 0, stream>>>(bmax, mx);
    accum_kernel<<<LOGIT_BLOCKS, 256, 0, stream>>>(xb, selc, selw, sell, nsel, mx, S, zp);

    // final scores
    score_kernel<<<(BATCH * 64 + 255) / 256, 256, 0, stream>>>(xb, users, items, S, zp, out);
}

// Round 15
// 312.317 us; speedup vs baseline: 1.8385x; 1.0603x over previous
//
#include <hip/hip_runtime.h>
#include <float.h>
#include <math.h>

#define NUM_USERS 100000
#define NUM_ITEMS 50000
#define NNODES    150000
#define DIM       64
#define NEDGE     2000000
#define BATCH     1024
#define SEL_CAP   (1 << 18)
#define LOGIT_BLOCKS 512

#define SLICES   512                    // edge slices
#define EPS      3908                   // ceil(NEDGE/SLICES) rounded to x4
#define NBUK     293                    // buckets of 512 nodes (293*512=150016)

__device__ __forceinline__ float wave_sum64(float v) {
    #pragma unroll
    for (int off = 32; off > 0; off >>= 1) v += __shfl_xor(v, off, 64);
    return v;
}

__device__ __forceinline__ float bf2f(unsigned short s) {
    return __uint_as_float(((unsigned int)s) << 16);
}
__device__ __forceinline__ unsigned short f2bf(float f) {   // RNE
    unsigned int u = __float_as_uint(f);
    return (unsigned short)((u + 0x7fffu + ((u >> 16) & 1u)) >> 16);
}

// ---- stage 1: per-slice 293-bucket histograms + u8 ranks + fused selection

__global__ __launch_bounds__(512) void bhist_kernel(
        const int* __restrict__ row, const int* __restrict__ col,
        const int* __restrict__ ucnt,
        unsigned short* __restrict__ cntR, unsigned short* __restrict__ cntC,
        unsigned char* __restrict__ rkR, unsigned char* __restrict__ rkC,
        int* __restrict__ n_sel, int* __restrict__ sel_col, float* __restrict__ sel_w) {
    __shared__ unsigned int hr[NBUK], hc[NBUK];
    __shared__ int lcnt, lbase;
    __shared__ int2 buf[256];
    int blk = blockIdx.x, t = threadIdx.x;
    for (int i = t; i < NBUK; i += 512) { hr[i] = 0; hc[i] = 0; }
    if (t == 0) lcnt = 0;
    __syncthreads();
    int e0 = blk * EPS;
    int e1 = e0 + EPS; if (e1 > NEDGE) e1 = NEDGE;
    for (int base = e0 + t * 4; base < e1; base += 2048) {
        if (base + 4 <= e1) {
            int4 r4 = *(const int4*)(row + base);
            int4 c4 = *(const int4*)(col + base);
            uchar4 a, b;
            a.x = (unsigned char)atomicAdd(&hr[r4.x >> 9], 1u);
            a.y = (unsigned char)atomicAdd(&hr[r4.y >> 9], 1u);
            a.z = (unsigned char)atomicAdd(&hr[r4.z >> 9], 1u);
            a.w = (unsigned char)atomicAdd(&hr[r4.w >> 9], 1u);
            b.x = (unsigned char)atomicAdd(&hc[c4.x >> 9], 1u);
            b.y = (unsigned char)atomicAdd(&hc[c4.y >> 9], 1u);
            b.z = (unsigned char)atomicAdd(&hc[c4.z >> 9], 1u);
            b.w = (unsigned char)atomicAdd(&hc[c4.w >> 9], 1u);
            *(uchar4*)(rkR + base) = a;
            *(uchar4*)(rkC + base) = b;
            int u0 = ucnt[r4.x], u1 = ucnt[r4.y], u2 = ucnt[r4.z], u3 = ucnt[r4.w];
            if (u0 > 0) { int i = atomicAdd(&lcnt, 1); if (i < 256) buf[i] = make_int2(c4.x, u0); }
            if (u1 > 0) { int i = atomicAdd(&lcnt, 1); if (i < 256) buf[i] = make_int2(c4.y, u1); }
            if (u2 > 0) { int i = atomicAdd(&lcnt, 1); if (i < 256) buf[i] = make_int2(c4.z, u2); }
            if (u3 > 0) { int i = atomicAdd(&lcnt, 1); if (i < 256) buf[i] = make_int2(c4.w, u3); }
        } else {
            for (int e = base; e < e1; ++e) {
                int r = row[e], c = col[e];
                rkR[e] = (unsigned char)atomicAdd(&hr[r >> 9], 1u);
                rkC[e] = (unsigned char)atomicAdd(&hc[c >> 9], 1u);
                int u = ucnt[r];
                if (u > 0) { int i = atomicAdd(&lcnt, 1); if (i < 256) buf[i] = make_int2(c, u); }
            }
        }
    }
    __syncthreads();
    for (int i = t; i < NBUK; i += 512) {
        cntR[(size_t)blk * NBUK + i] = (unsigned short)hr[i];
        cntC[(size_t)blk * NBUK + i] = (unsigned short)hc[i];
    }
    if (t == 0) {
        int c = lcnt; c = c < 256 ? c : 256;
        lbase = atomicAdd(n_sel, c);
    }
    __syncthreads();
    int c = lcnt; c = c < 256 ? c : 256;
    int b = lbase;
    for (int i = t; i < c; i += 512) {
        int o = b + i;
        if (o < SEL_CAP) { sel_col[o] = buf[i].x; sel_w[o] = (float)buf[i].y; }
    }
}

// ---- stage 2: parallel per-bucket prefix over slices ---------------------

__global__ __launch_bounds__(512) void bprefix1_kernel(
        const unsigned short* __restrict__ cntR, const unsigned short* __restrict__ cntC,
        unsigned short* __restrict__ offR, unsigned short* __restrict__ offC,
        int* __restrict__ totRC) {
    int side = blockIdx.x / NBUK;
    int b = blockIdx.x - side * NBUK;
    const unsigned short* cnt = side ? cntC : cntR;
    unsigned short* off = side ? offC : offR;
    __shared__ int sm[512];
    int t = threadIdx.x;
    int v = (int)cnt[(size_t)t * NBUK + b];
    sm[t] = v;
    __syncthreads();
    for (int o = 1; o < 512; o <<= 1) {
        int x = (t >= o) ? sm[t - o] : 0;
        __syncthreads();
        sm[t] += x;
        __syncthreads();
    }
    off[(size_t)t * NBUK + b] = (unsigned short)(sm[t] - v);
    if (t == 511) totRC[side * NBUK + b] = sm[511];
}

__global__ __launch_bounds__(512) void bprefix2_kernel(
        const int* __restrict__ totRC, int* __restrict__ baseR, int* __restrict__ baseC) {
    const int* tot = totRC + blockIdx.x * NBUK;
    int* base = blockIdx.x ? baseC : baseR;
    __shared__ int sm[512];
    int t = threadIdx.x;
    int v = (t < NBUK) ? tot[t] : 0;
    sm[t] = v;
    __syncthreads();
    for (int o = 1; o < 512; o <<= 1) {
        int x = (t >= o) ? sm[t - o] : 0;
        __syncthreads();
        sm[t] += x;
        __syncthreads();
    }
    if (t < NBUK) base[t] = sm[t] - v;
    if (t == NBUK - 1) base[NBUK] = sm[t];     // == NEDGE
}

// ---- stage 3: placement -- pure LDS-staged slice sort, burst write-out ---

__global__ __launch_bounds__(512) void place_kernel(
        const int* __restrict__ row, const int* __restrict__ col,
        const unsigned char* __restrict__ rkR, const unsigned char* __restrict__ rkC,
        const unsigned short* __restrict__ cntR, const unsigned short* __restrict__ cntC,
        const unsigned short* __restrict__ offR, const unsigned short* __restrict__ offC,
        const int* __restrict__ baseR, const int* __restrict__ baseC,
        unsigned short* __restrict__ midR, unsigned int* __restrict__ midC) {
    __shared__ int lofC[NBUK], lofR[NBUK], posC[NBUK], posR[NBUK];
    __shared__ int cCl[NBUK], cRl[NBUK];
    __shared__ int scan_tmp[512];
    __shared__ unsigned int   stC[EPS];
    __shared__ unsigned short stR[EPS];
    int blk = blockIdx.x, t = threadIdx.x;
    if (t < NBUK) {
        cCl[t] = (int)cntC[(size_t)blk * NBUK + t];
        cRl[t] = (int)cntR[(size_t)blk * NBUK + t];
        posC[t] = baseC[t] + (int)offC[(size_t)blk * NBUK + t];
        posR[t] = baseR[t] + (int)offR[(size_t)blk * NBUK + t];
    }
    __syncthreads();
    scan_tmp[t] = (t < NBUK) ? cCl[t] : 0;
    __syncthreads();
    for (int o = 1; o < 512; o <<= 1) {
        int v = (t >= o) ? scan_tmp[t - o] : 0;
        __syncthreads();
        scan_tmp[t] += v;
        __syncthreads();
    }
    if (t < NBUK) lofC[t] = scan_tmp[t] - cCl[t];
    __syncthreads();
    scan_tmp[t] = (t < NBUK) ? cRl[t] : 0;
    __syncthreads();
    for (int o = 1; o < 512; o <<= 1) {
        int v = (t >= o) ? scan_tmp[t - o] : 0;
        __syncthreads();
        scan_tmp[t] += v;
        __syncthreads();
    }
    if (t < NBUK) lofR[t] = scan_tmp[t] - cRl[t];
    __syncthreads();
    int e0 = blk * EPS;
    int e1 = e0 + EPS; if (e1 > NEDGE) e1 = NEDGE;
    for (int base = e0 + t * 4; base < e1; base += 2048) {
        if (base + 4 <= e1) {
            int4 r4 = *(const int4*)(row + base);
            int4 c4 = *(const int4*)(col + base);
            uchar4 kr = *(const uchar4*)(rkR + base);
            uchar4 kc = *(const uchar4*)(rkC + base);
            stC[lofC[c4.x >> 9] + (int)kc.x] = ((unsigned int)(c4.x & 511) << 18) | (unsigned int)r4.x;
            stC[lofC[c4.y >> 9] + (int)kc.y] = ((unsigned int)(c4.y & 511) << 18) | (unsigned int)r4.y;
            stC[lofC[c4.z >> 9] + (int)kc.z] = ((unsigned int)(c4.z & 511) << 18) | (unsigned int)r4.z;
            stC[lofC[c4.w >> 9] + (int)kc.w] = ((unsigned int)(c4.w & 511) << 18) | (unsigned int)r4.w;
            stR[lofR[r4.x >> 9] + (int)kr.x] = (unsigned short)(r4.x & 511);
            stR[lofR[r4.y >> 9] + (int)kr.y] = (unsigned short)(r4.y & 511);
            stR[lofR[r4.z >> 9] + (int)kr.z] = (unsigned short)(r4.z & 511);
            stR[lofR[r4.w >> 9] + (int)kr.w] = (unsigned short)(r4.w & 511);
        } else {
            for (int e = base; e < e1; ++e) {
                int r = row[e], c = col[e];
                stC[lofC[c >> 9] + (int)rkC[e]] = ((unsigned int)(c & 511) << 18) | (unsigned int)r;
                stR[lofR[r >> 9] + (int)rkR[e]] = (unsigned short)(r & 511);
            }
        }
    }
    __syncthreads();
    int wave = t >> 6, lane = t & 63;
    for (int b = wave; b < NBUK; b += 8) {
        int n = cCl[b], lo = lofC[b], dst = posC[b];
        for (int i = lane; i < n; i += 64) midC[dst + i] = stC[lo + i];
        n = cRl[b]; lo = lofR[b]; dst = posR[b];
        for (int i = lane; i < n; i += 64) midR[dst + i] = stR[lo + i];
    }
}

// ---- stage 4 (fused): col CSR + row deg/dinv + embed->bf16 y0 ------------
// Block b: col bucket b (rptr + permute), row bucket b (deg -> dinv/dinv2),
// then converts nodes [b*512, b*512+512) of embed to y0 = dinv*x0 (bf16).

__global__ __launch_bounds__(1024) void bfinal_kernel(
        const unsigned int* __restrict__ midC, const int* __restrict__ baseC,
        const unsigned short* __restrict__ midR, const int* __restrict__ baseR,
        const float4* __restrict__ embed,
        int* __restrict__ rptr, int* __restrict__ src_sorted,
        float* __restrict__ dinv, float* __restrict__ dinv2,
        uint2* __restrict__ y0) {
    __shared__ int cnt[512], sm[512], cur[512];
    __shared__ float dinvL[512];
    int b = blockIdx.x, t = threadIdx.x;
    // --- col part ---
    int s0 = baseC[b], s1 = baseC[b + 1];
    if (t < 512) cnt[t] = 0;
    __syncthreads();
    for (int i = s0 + t; i < s1; i += 1024) atomicAdd(&cnt[midC[i] >> 18], 1);
    __syncthreads();
    if (t < 512) sm[t] = cnt[t];
    __syncthreads();
    for (int off = 1; off < 512; off <<= 1) {
        int v = 0;
        if (t < 512 && t >= off) v = sm[t - off];
        __syncthreads();
        if (t < 512) sm[t] += v;
        __syncthreads();
    }
    if (t < 512) {
        int excl = s0 + sm[t] - cnt[t];
        int n = b * 512 + t;
        if (n < NNODES) rptr[n] = excl;
        cur[t] = excl;
    }
    if (b == NBUK - 1 && t == 0) rptr[NNODES] = s1;   // == NEDGE
    __syncthreads();
    for (int i = s0 + t; i < s1; i += 1024) {
        unsigned int v = midC[i];
        int dst = atomicAdd(&cur[v >> 18], 1);
        src_sorted[dst] = (int)(v & 0x3FFFFu);
    }
    __syncthreads();
    // --- row part ---
    if (t < 512) cnt[t] = 0;
    __syncthreads();
    int r0 = baseR[b], r1 = baseR[b + 1];
    for (int i = r0 + t; i < r1; i += 1024) atomicAdd(&cnt[midR[i]], 1);
    __syncthreads();
    if (t < 512) {
        int n = b * 512 + t;
        if (n < NNODES) {
            float d = fmaxf((float)cnt[t], 1.0f);
            float di = rsqrtf(d);
            dinv[n] = di; dinv2[n] = 1.0f / d;
            dinvL[t] = di;
        }
    }
    __syncthreads();
    // --- cvt part: y0 = bf16(dinv * embed) for this node range ---
    int nbase = b * 512;
    int nmax = NNODES - nbase; if (nmax > 512) nmax = 512;
    if (nmax < 0) nmax = 0;
    for (int i = t; i < nmax * 16; i += 1024) {
        int ln = i >> 4, slot = i & 15;
        float d = dinvL[ln];
        float4 v = embed[(size_t)(nbase + ln) * 16 + slot];
        unsigned int w0 = (unsigned int)f2bf(v.x * d) | ((unsigned int)f2bf(v.y * d) << 16);
        unsigned int w1 = (unsigned int)f2bf(v.z * d) | ((unsigned int)f2bf(v.w * d) << 16);
        y0[(size_t)(nbase + ln) * 16 + slot] = make_uint2(w0, w1);
    }
}

// ---- propagation: 8 lanes/node, uint4 (8 bf16) per lane ------------------

__global__ void prop_kernel(const uint4* __restrict__ x_in, uint4* __restrict__ x_out,
                            const int* __restrict__ ptr, const int* __restrict__ src,
                            const float* __restrict__ scale) {
    int gid  = blockIdx.x * blockDim.x + threadIdx.x;
    int node = gid >> 3;       // 8 lanes per node
    int sl   = gid & 7;        // lane's 8-dim slot within the row
    if (node >= NNODES) return;
    int s = ptr[node], e = ptr[node + 1];
    float a0 = 0.f, a1 = 0.f, a2 = 0.f, a3 = 0.f;
    float a4 = 0.f, a5 = 0.f, a6 = 0.f, a7 = 0.f;
    int i = s;
    for (; i + 4 <= e; i += 4) {
        int s0 = src[i], s1 = src[i + 1], s2 = src[i + 2], s3 = src[i + 3];
        uint4 w0 = x_in[s0 * 8 + sl];
        uint4 w1 = x_in[s1 * 8 + sl];
        uint4 w2 = x_in[s2 * 8 + sl];
        uint4 w3 = x_in[s3 * 8 + sl];
        a0 += __uint_as_float(w0.x << 16); a1 += __uint_as_float(w0.x & 0xffff0000u);
        a2 += __uint_as_float(w0.y << 16); a3 += __uint_as_float(w0.y & 0xffff0000u);
        a4 += __uint_as_float(w0.z << 16); a5 += __uint_as_float(w0.z & 0xffff0000u);
        a6 += __uint_as_float(w0.w << 16); a7 += __uint_as_float(w0.w & 0xffff0000u);
        a0 += __uint_as_float(w1.x << 16); a1 += __uint_as_float(w1.x & 0xffff0000u);
        a2 += __uint_as_float(w1.y << 16); a3 += __uint_as_float(w1.y & 0xffff0000u);
        a4 += __uint_as_float(w1.z << 16); a5 += __uint_as_float(w1.z & 0xffff0000u);
        a6 += __uint_as_float(w1.w << 16); a7 += __uint_as_float(w1.w & 0xffff0000u);
        a0 += __uint_as_float(w2.x << 16); a1 += __uint_as_float(w2.x & 0xffff0000u);
        a2 += __uint_as_float(w2.y << 16); a3 += __uint_as_float(w2.y & 0xffff0000u);
        a4 += __uint_as_float(w2.z << 16); a5 += __uint_as_float(w2.z & 0xffff0000u);
        a6 += __uint_as_float(w2.w << 16); a7 += __uint_as_float(w2.w & 0xffff0000u);
        a0 += __uint_as_float(w3.x << 16); a1 += __uint_as_float(w3.x & 0xffff0000u);
        a2 += __uint_as_float(w3.y << 16); a3 += __uint_as_float(w3.y & 0xffff0000u);
        a4 += __uint_as_float(w3.z << 16); a5 += __uint_as_float(w3.z & 0xffff0000u);
        a6 += __uint_as_float(w3.w << 16); a7 += __uint_as_float(w3.w & 0xffff0000u);
    }
    for (; i < e; ++i) {
        uint4 w0 = x_in[src[i] * 8 + sl];
        a0 += __uint_as_float(w0.x << 16); a1 += __uint_as_float(w0.x & 0xffff0000u);
        a2 += __uint_as_float(w0.y << 16); a3 += __uint_as_float(w0.y & 0xffff0000u);
        a4 += __uint_as_float(w0.z << 16); a5 += __uint_as_float(w0.z & 0xffff0000u);
        a6 += __uint_as_float(w0.w << 16); a7 += __uint_as_float(w0.w & 0xffff0000u);
    }
    float sc = scale[node];
    uint4 o;
    o.x = (unsigned int)f2bf(a0 * sc) | ((unsigned int)f2bf(a1 * sc) << 16);
    o.y = (unsigned int)f2bf(a2 * sc) | ((unsigned int)f2bf(a3 * sc) << 16);
    o.z = (unsigned int)f2bf(a4 * sc) | ((unsigned int)f2bf(a5 * sc) << 16);
    o.w = (unsigned int)f2bf(a6 * sc) | ((unsigned int)f2bf(a7 * sc) << 16);
    x_out[node * 8 + sl] = o;
}

// ---- batch / softmax part (x is bf16) -----------------------------------

__global__ void ucnt_kernel(const int* __restrict__ users, int* __restrict__ ucnt) {
    int b = blockIdx.x * blockDim.x + threadIdx.x;
    if (b < BATCH) atomicAdd(&ucnt[users[b]], 1);
}

// ctx phase 1: 256 blocks x 4 waves; wave w of block b loads user row 4b+w.
__global__ __launch_bounds__(256) void ctx_part_kernel(
        const unsigned short* __restrict__ x, const int* __restrict__ users,
        float* __restrict__ partial) {
    __shared__ float sm[256];
    int lane = threadIdx.x & 63, wl = threadIdx.x >> 6;
    int b = blockIdx.x * 4 + wl;
    float v = (b < BATCH) ? bf2f(x[users[b] * DIM + lane]) : 0.0f;
    sm[threadIdx.x] = v;
    __syncthreads();
    if (wl == 0)
        partial[blockIdx.x * 64 + lane] =
            sm[lane] + sm[64 + lane] + sm[128 + lane] + sm[192 + lane];
}

// ctx phase 2: reduce 256 partials -> ctx (mean over BATCH)
__global__ __launch_bounds__(256) void ctx_reduce_kernel(
        const float* __restrict__ partial, float* __restrict__ ctx) {
    __shared__ float sm[256];
    int lane = threadIdx.x & 63, wl = threadIdx.x >> 6;
    float acc = 0.0f;
    for (int i = wl; i < 256; i += 4) acc += partial[i * 64 + lane];
    sm[threadIdx.x] = acc;
    __syncthreads();
    if (wl == 0)
        ctx[lane] = (sm[lane] + sm[64 + lane] + sm[128 + lane] + sm[192 + lane])
                    * (1.0f / BATCH);
}

// fused logit+accum: S/z is invariant to the softmax shift, and logits are
// bounded (|x . ctx| ~ O(1)), so mx = 0: one x-gather per edge, one kernel.
__global__ void softmax_kernel(const unsigned short* __restrict__ x,
                               const float* __restrict__ ctx,
                               const int* __restrict__ sel_col,
                               const float* __restrict__ sel_w,
                               const int* __restrict__ n_sel_p,
                               float* __restrict__ S, float* __restrict__ zp) {
    __shared__ float smS[4 * 64];
    __shared__ float smZ[4];
    int lane = threadIdx.x & 63, wl = threadIdx.x >> 6;
    int n = *n_sel_p; if (n > SEL_CAP) n = SEL_CAP;
    float c = ctx[lane];
    float accS = 0.0f, accZ = 0.0f;
    int stride = gridDim.x * 4;
    for (int idx = blockIdx.x * 4 + wl; idx < n; idx += stride) {
        int node = sel_col[idx];
        float xv = bf2f(x[node * DIM + lane]);
        float v = wave_sum64(xv * c);
        float w = sel_w[idx] * __expf(v);
        accS = fmaf(w, xv, accS);
        accZ += w;
    }
    smS[wl * 64 + lane] = accS;
    if (lane == 0) smZ[wl] = accZ;
    __syncthreads();
    if (wl == 0) {
        float s = smS[lane] + smS[64 + lane] + smS[128 + lane] + smS[192 + lane];
        atomicAdd(&S[lane], s);
    }
    if (threadIdx.x == 0) atomicAdd(zp, smZ[0] + smZ[1] + smZ[2] + smZ[3]);
}

__global__ void score_kernel(const unsigned short* __restrict__ x, const int* __restrict__ users,
                             const int* __restrict__ items, const float* __restrict__ S,
                             const float* __restrict__ zp, float* __restrict__ out) {
    int gid = blockIdx.x * blockDim.x + threadIdx.x;
    int b = gid >> 6, lane = gid & 63;
    if (b >= BATCH) return;
    float z = fmaxf(*zp, 1e-12f);
    float na = S[lane] / z;
    int u = users[b], it = items[b] + NUM_USERS;
    float v = bf2f(x[u * DIM + lane]) * (bf2f(x[it * DIM + lane]) + na);
    v = wave_sum64(v);
    if (lane == 0) out[b] = 1.0f / (1.0f + __expf(-v));
}

// ---- launch -------------------------------------------------------------

extern "C" void kernel_launch(void* const* d_in, const int* in_sizes, int n_in,
                              void* d_out, int out_size, void* d_ws, size_t ws_size,
                              hipStream_t stream) {
    const float* embed = (const float*)d_in[0];
    const int*   edge  = (const int*)d_in[1];
    const int*   row   = edge;
    const int*   col   = edge + NEDGE;
    const int*   users = (const int*)d_in[2];
    const int*   items = (const int*)d_in[3];
    float*       out   = (float*)d_out;
    char*        ws    = (char*)d_ws;

    size_t off = 0;
    auto A = [&](size_t bytes) { size_t o = off; off += (bytes + 255) & ~(size_t)255; return o; };
    size_t o_mid   = A((size_t)NEDGE * 4 + (size_t)NEDGE * 2);  // midC 8MB + midR 4MB
    size_t o_xa    = A((size_t)NNODES * DIM * 2);      // 19.2 MB (no overlay: bfinal
    size_t o_xb    = A((size_t)NNODES * DIM * 2);      //  writes y0 while mid is read)
    size_t o_src   = A((size_t)NEDGE * 4);             // 8 MB, alive thru prop
    size_t o_rkR   = A((size_t)SLICES * EPS);          // 2 MB
    size_t o_rkC   = A((size_t)SLICES * EPS);          // 2 MB
    size_t o_cntR  = A((size_t)SLICES * NBUK * 2);     // 300 KB
    size_t o_cntC  = A((size_t)SLICES * NBUK * 2);
    size_t o_offR  = A((size_t)SLICES * NBUK * 2);
    size_t o_offC  = A((size_t)SLICES * NBUK * 2);
    size_t o_tot   = A((size_t)2 * NBUK * 4);
    size_t o_baseR = A((size_t)(NBUK + 1) * 4);
    size_t o_baseC = A((size_t)(NBUK + 1) * 4);
    size_t o_selc  = A((size_t)SEL_CAP * 4);
    size_t o_selw  = A((size_t)SEL_CAP * 4);
    size_t o_part  = A((size_t)256 * 64 * 4);          // ctx partials
    size_t o_zero  = off;                              // ---- zeroed block ----
    size_t o_ucnt  = A((size_t)NNODES * 4);
    size_t o_misc  = A(1024);                          // n_sel@0, z@8, S@256
    size_t zero_bytes = off - o_zero;                  // ---- end zero -------
    size_t o_dinv  = A((size_t)NNODES * 4);
    size_t o_dinv2 = A((size_t)NNODES * 4);
    size_t o_rptr  = A((size_t)(NNODES + 1) * 4);
    size_t o_ctx   = A(256);

    unsigned int*   midC = (unsigned int*)(ws + o_mid);
    unsigned short* midR = (unsigned short*)(ws + o_mid + (size_t)NEDGE * 4);
    unsigned short* xa   = (unsigned short*)(ws + o_xa);
    unsigned short* xb   = (unsigned short*)(ws + o_xb);
    int*   srcS  = (int*)(ws + o_src);
    unsigned char* rkR = (unsigned char*)(ws + o_rkR);
    unsigned char* rkC = (unsigned char*)(ws + o_rkC);
    unsigned short* cntR = (unsigned short*)(ws + o_cntR);
    unsigned short* cntC = (unsigned short*)(ws + o_cntC);
    unsigned short* offR = (unsigned short*)(ws + o_offR);
    unsigned short* offC = (unsigned short*)(ws + o_offC);
    int*   totRC = (int*)(ws + o_tot);
    int*   baseR = (int*)(ws + o_baseR);
    int*   baseC = (int*)(ws + o_baseC);
    int*   selc  = (int*)(ws + o_selc);
    float* selw  = (float*)(ws + o_selw);
    float* part  = (float*)(ws + o_part);
    int*   ucnt  = (int*)(ws + o_ucnt);
    int*   nsel  = (int*)(ws + o_misc);
    float* zp    = (float*)(ws + o_misc + 8);
    float* S     = (float*)(ws + o_misc + 256);
    float* dinv  = (float*)(ws + o_dinv);
    float* dinv2 = (float*)(ws + o_dinv2);
    int*   rptr  = (int*)(ws + o_rptr);
    float* ctx   = (float*)(ws + o_ctx);

    hipMemsetAsync(ws + o_zero, 0, zero_bytes, stream);

    ucnt_kernel<<<(BATCH + 255) / 256, 256, 0, stream>>>(users, ucnt);

    // atomic-free CSR build (selection fused into bhist)
    bhist_kernel<<<SLICES, 512, 0, stream>>>(row, col, ucnt, cntR, cntC, rkR, rkC,
                                             nsel, selc, selw);
    bprefix1_kernel<<<2 * NBUK, 512, 0, stream>>>(cntR, cntC, offR, offC, totRC);
    bprefix2_kernel<<<2, 512, 0, stream>>>(totRC, baseR, baseC);
    place_kernel<<<SLICES, 512, 0, stream>>>(row, col, rkR, rkC, cntR, cntC,
                                             offR, offC, baseR, baseC, midR, midC);
    // fused: col CSR + row deg + embed->y0 conversion
    bfinal_kernel<<<NBUK, 1024, 0, stream>>>(midC, baseC, midR, baseR,
                                             (const float4*)embed, rptr, srcS,
                                             dinv, dinv2, (uint2*)xa);

    // layers: y->y (dinv2), y->y (dinv2), y->x (dinv)
    int prop_blocks = (NNODES * 8 + 255) / 256;
    prop_kernel<<<prop_blocks, 256, 0, stream>>>((const uint4*)xa, (uint4*)xb, rptr, srcS, dinv2);
    prop_kernel<<<prop_blocks, 256, 0, stream>>>((const uint4*)xb, (uint4*)xa, rptr, srcS, dinv2);
    prop_kernel<<<prop_blocks, 256, 0, stream>>>((const uint4*)xa, (uint4*)xb, rptr, srcS, dinv);
    // final x lives in xb

    // batch softmax aggregation over selected edges (mx = 0, fused)
    ctx_part_kernel<<<256, 256, 0, stream>>>(xb, users, part);
    ctx_reduce_kernel<<<1, 256, 0, stream>>>(part, ctx);
    softmax_kernel<<<LOGIT_BLOCKS, 256, 0, stream>>>(xb, ctx, selc, selw, nsel, S, zp);

    // final scores
    score_kernel<<<(BATCH * 64 + 255) / 256, 256, 0, stream>>>(xb, users, items, S, zp, out);
}